// Round 1
// baseline (1271.585 us; speedup 1.0000x reference)
//
#include <hip/hip_runtime.h>
#include <cstddef>
#include <cstdint>
#include <math.h>

// Problem constants
constexpr int B  = 2;
constexpr int S  = 2048;
constexpr int D  = 1024;
constexpr int H  = 16;
constexpr int HD = 64;          // head dim
constexpr int BH = B * H;       // 32
constexpr size_t QSZ = (size_t)B * H * S * HD;   // 4,194,304 floats per tensor
constexpr float SCALE = 0.125f; // 1/sqrt(64)

// ---------------------------------------------------------------------------
// Kernel 1: QKV projection.  C[m][n] = x[m][:] @ W_qkv[:][n] + b_qkv[n]
// m = b*S + s  (M = 4096), n in [0,3072).
// Column mapping (from reshape(B,S,H,3*hd) then split):
//   h = n/192, r = n%192, t = r/64 (0=q,1=k,2=v), d = r%64
// Scatter into Q/K/V stored [B,H,S,HD].
// ---------------------------------------------------------------------------
__global__ __launch_bounds__(256) void k_qkv(const float* __restrict__ A,
                                             const float* __restrict__ W,
                                             const float* __restrict__ bias,
                                             float* __restrict__ Q,
                                             float* __restrict__ Kt,
                                             float* __restrict__ V)
{
    __shared__ float As[16][64];   // [k][m]
    __shared__ float Bs[16][64];   // [k][n]
    const int tid = threadIdx.x;
    const int tx = tid & 15, ty = tid >> 4;
    const int row0 = blockIdx.y * 64;
    const int col0 = blockIdx.x * 64;

    const int arow = tid >> 2, ak4 = tid & 3;   // A tile: 64 rows x 16 k
    const int bk   = tid >> 4, bn4 = tid & 15;  // B tile: 16 k x 64 n

    float acc[4][4] = {};

    for (int k0 = 0; k0 < D; k0 += 16) {
        float4 av = *(const float4*)(A + (size_t)(row0 + arow) * D + k0 + ak4 * 4);
        float4 bv = *(const float4*)(W + (size_t)(k0 + bk) * (3 * D) + col0 + bn4 * 4);
        __syncthreads();
        As[ak4 * 4 + 0][arow] = av.x;
        As[ak4 * 4 + 1][arow] = av.y;
        As[ak4 * 4 + 2][arow] = av.z;
        As[ak4 * 4 + 3][arow] = av.w;
        *(float4*)&Bs[bk][bn4 * 4] = bv;
        __syncthreads();
#pragma unroll
        for (int kk = 0; kk < 16; ++kk) {
            float4 a4 = *(const float4*)&As[kk][ty * 4];
            float4 b4 = *(const float4*)&Bs[kk][tx * 4];
            float a[4] = {a4.x, a4.y, a4.z, a4.w};
            float b[4] = {b4.x, b4.y, b4.z, b4.w};
#pragma unroll
            for (int i = 0; i < 4; ++i)
#pragma unroll
                for (int j = 0; j < 4; ++j) acc[i][j] += a[i] * b[j];
        }
    }

    // epilogue: scatter (4 consecutive n never cross a 64-col q/k/v boundary)
    const int n0 = col0 + tx * 4;
    const int h  = n0 / 192;
    const int r  = n0 % 192;
    const int t  = r >> 6;
    const int d  = r & 63;
    float* dst = (t == 0) ? Q : (t == 1) ? Kt : V;
    const float b0 = bias[n0 + 0], b1 = bias[n0 + 1], b2 = bias[n0 + 2], b3 = bias[n0 + 3];
#pragma unroll
    for (int i = 0; i < 4; ++i) {
        const int m = row0 + ty * 4 + i;
        const int bb = m >> 11;        // m / S
        const int ss = m & (S - 1);    // m % S
        float4 v = {acc[i][0] + b0, acc[i][1] + b1, acc[i][2] + b2, acc[i][3] + b3};
        *(float4*)(dst + (((size_t)bb * H + h) * S + ss) * HD + d) = v;
    }
}

// ---------------------------------------------------------------------------
// Kernel 2: scores[bh][i][j] = SCALE * sum_d Q[bh][i][d] * K[bh][j][d]
// Written pre-softmax into the attention output region.
// ---------------------------------------------------------------------------
__global__ __launch_bounds__(256) void k_scores(const float* __restrict__ Q,
                                                const float* __restrict__ Kt,
                                                float* __restrict__ attn)
{
    __shared__ float Qs[64][64];   // [k][m]
    __shared__ float Ks[64][64];   // [k][n]
    const int tid = threadIdx.x;
    const int tx = tid & 15, ty = tid >> 4;
    const int bh = blockIdx.z;
    const float* Qb = Q  + (size_t)bh * S * HD;
    const float* Kb = Kt + (size_t)bh * S * HD;
    const int row0 = blockIdx.y * 64;
    const int col0 = blockIdx.x * 64;

#pragma unroll
    for (int i = 0; i < 4; ++i) {
        const int f  = tid + 256 * i;
        const int rr = f >> 4;      // 0..63
        const int k4 = f & 15;      // 0..15
        float4 qv = *(const float4*)(Qb + (size_t)(row0 + rr) * HD + k4 * 4);
        float4 kv = *(const float4*)(Kb + (size_t)(col0 + rr) * HD + k4 * 4);
        Qs[k4 * 4 + 0][rr] = qv.x; Qs[k4 * 4 + 1][rr] = qv.y;
        Qs[k4 * 4 + 2][rr] = qv.z; Qs[k4 * 4 + 3][rr] = qv.w;
        Ks[k4 * 4 + 0][rr] = kv.x; Ks[k4 * 4 + 1][rr] = kv.y;
        Ks[k4 * 4 + 2][rr] = kv.z; Ks[k4 * 4 + 3][rr] = kv.w;
    }
    __syncthreads();

    float acc[4][4] = {};
#pragma unroll 16
    for (int kk = 0; kk < 64; ++kk) {
        float4 a4 = *(const float4*)&Qs[kk][ty * 4];
        float4 b4 = *(const float4*)&Ks[kk][tx * 4];
        float a[4] = {a4.x, a4.y, a4.z, a4.w};
        float b[4] = {b4.x, b4.y, b4.z, b4.w};
#pragma unroll
        for (int i = 0; i < 4; ++i)
#pragma unroll
            for (int j = 0; j < 4; ++j) acc[i][j] += a[i] * b[j];
    }

    float* out = attn + (size_t)bh * S * S;
#pragma unroll
    for (int i = 0; i < 4; ++i) {
        const int rr = row0 + ty * 4 + i;
        float4 v = {acc[i][0] * SCALE, acc[i][1] * SCALE,
                    acc[i][2] * SCALE, acc[i][3] * SCALE};
        *(float4*)(out + (size_t)rr * S + col0 + tx * 4) = v;
    }
}

// ---------------------------------------------------------------------------
// Kernel 3: in-place row softmax over rows of length S=2048.
// One block (256 threads) per row; 8 elements/thread.
// ---------------------------------------------------------------------------
__global__ __launch_bounds__(256) void k_softmax(float* __restrict__ attn)
{
    const size_t row = blockIdx.x;
    float* p = attn + row * S;
    const int tid = threadIdx.x;

    float4 v0 = *(const float4*)(p + tid * 4);
    float4 v1 = *(const float4*)(p + 1024 + tid * 4);

    float m = fmaxf(fmaxf(fmaxf(v0.x, v0.y), fmaxf(v0.z, v0.w)),
                    fmaxf(fmaxf(v1.x, v1.y), fmaxf(v1.z, v1.w)));
#pragma unroll
    for (int off = 32; off > 0; off >>= 1) m = fmaxf(m, __shfl_xor(m, off));

    __shared__ float redm[4];
    __shared__ float reds[4];
    const int wave = tid >> 6, lane = tid & 63;
    if (lane == 0) redm[wave] = m;
    __syncthreads();
    m = fmaxf(fmaxf(redm[0], redm[1]), fmaxf(redm[2], redm[3]));

    float e[8];
    e[0] = expf(v0.x - m); e[1] = expf(v0.y - m);
    e[2] = expf(v0.z - m); e[3] = expf(v0.w - m);
    e[4] = expf(v1.x - m); e[5] = expf(v1.y - m);
    e[6] = expf(v1.z - m); e[7] = expf(v1.w - m);
    float sum = 0.f;
#pragma unroll
    for (int i = 0; i < 8; ++i) sum += e[i];
#pragma unroll
    for (int off = 32; off > 0; off >>= 1) sum += __shfl_xor(sum, off);
    if (lane == 0) reds[wave] = sum;
    __syncthreads();
    sum = (reds[0] + reds[1]) + (reds[2] + reds[3]);

    const float inv = 1.0f / sum;
    float4 o0 = {e[0] * inv, e[1] * inv, e[2] * inv, e[3] * inv};
    float4 o1 = {e[4] * inv, e[5] * inv, e[6] * inv, e[7] * inv};
    *(float4*)(p + tid * 4) = o0;
    *(float4*)(p + 1024 + tid * 4) = o1;
}

// ---------------------------------------------------------------------------
// Kernel 4: values[bh][i][d] = sum_k P[bh][i][k] * V[bh][k][d]
// Output written to vt laid out [B,S,H,HD] (== [B,S,D]).
// ---------------------------------------------------------------------------
__global__ __launch_bounds__(256) void k_pv(const float* __restrict__ attn,
                                            const float* __restrict__ V,
                                            float* __restrict__ vt)
{
    __shared__ float As[16][64];   // [k][m] slice of P
    __shared__ float Bs[16][64];   // [k][d] slice of V
    const int tid = threadIdx.x;
    const int tx = tid & 15, ty = tid >> 4;
    const int bh = blockIdx.y;
    const int bb = bh >> 4, hh = bh & 15;
    const float* Pb = attn + (size_t)bh * S * S;
    const float* Vb = V    + (size_t)bh * S * HD;
    const int row0 = blockIdx.x * 64;

    const int arow = tid >> 2, ak4 = tid & 3;
    const int bk   = tid >> 4, bn4 = tid & 15;

    float acc[4][4] = {};
    for (int k0 = 0; k0 < S; k0 += 16) {
        float4 av = *(const float4*)(Pb + (size_t)(row0 + arow) * S + k0 + ak4 * 4);
        float4 bv = *(const float4*)(Vb + (size_t)(k0 + bk) * HD + bn4 * 4);
        __syncthreads();
        As[ak4 * 4 + 0][arow] = av.x;
        As[ak4 * 4 + 1][arow] = av.y;
        As[ak4 * 4 + 2][arow] = av.z;
        As[ak4 * 4 + 3][arow] = av.w;
        *(float4*)&Bs[bk][bn4 * 4] = bv;
        __syncthreads();
#pragma unroll
        for (int kk = 0; kk < 16; ++kk) {
            float4 a4 = *(const float4*)&As[kk][ty * 4];
            float4 b4 = *(const float4*)&Bs[kk][tx * 4];
            float a[4] = {a4.x, a4.y, a4.z, a4.w};
            float b[4] = {b4.x, b4.y, b4.z, b4.w};
#pragma unroll
            for (int i = 0; i < 4; ++i)
#pragma unroll
                for (int j = 0; j < 4; ++j) acc[i][j] += a[i] * b[j];
        }
    }

#pragma unroll
    for (int i = 0; i < 4; ++i) {
        const int ss = row0 + ty * 4 + i;
        float4 v = {acc[i][0], acc[i][1], acc[i][2], acc[i][3]};
        *(float4*)(vt + (((size_t)bb * S + ss) * H + hh) * HD + tx * 4) = v;
    }
}

// ---------------------------------------------------------------------------
// Kernel 5: out = vt @ W_out + b_out   (M=4096, N=1024, K=1024)
// ---------------------------------------------------------------------------
__global__ __launch_bounds__(256) void k_out(const float* __restrict__ A,
                                             const float* __restrict__ W,
                                             const float* __restrict__ bias,
                                             float* __restrict__ C)
{
    __shared__ float As[16][64];
    __shared__ float Bs[16][64];
    const int tid = threadIdx.x;
    const int tx = tid & 15, ty = tid >> 4;
    const int row0 = blockIdx.y * 64;
    const int col0 = blockIdx.x * 64;

    const int arow = tid >> 2, ak4 = tid & 3;
    const int bk   = tid >> 4, bn4 = tid & 15;

    float acc[4][4] = {};
    for (int k0 = 0; k0 < D; k0 += 16) {
        float4 av = *(const float4*)(A + (size_t)(row0 + arow) * D + k0 + ak4 * 4);
        float4 bv = *(const float4*)(W + (size_t)(k0 + bk) * D + col0 + bn4 * 4);
        __syncthreads();
        As[ak4 * 4 + 0][arow] = av.x;
        As[ak4 * 4 + 1][arow] = av.y;
        As[ak4 * 4 + 2][arow] = av.z;
        As[ak4 * 4 + 3][arow] = av.w;
        *(float4*)&Bs[bk][bn4 * 4] = bv;
        __syncthreads();
#pragma unroll
        for (int kk = 0; kk < 16; ++kk) {
            float4 a4 = *(const float4*)&As[kk][ty * 4];
            float4 b4 = *(const float4*)&Bs[kk][tx * 4];
            float a[4] = {a4.x, a4.y, a4.z, a4.w};
            float b[4] = {b4.x, b4.y, b4.z, b4.w};
#pragma unroll
            for (int i = 0; i < 4; ++i)
#pragma unroll
                for (int j = 0; j < 4; ++j) acc[i][j] += a[i] * b[j];
        }
    }

    const int n0 = col0 + tx * 4;
    const float b0 = bias[n0 + 0], b1 = bias[n0 + 1], b2 = bias[n0 + 2], b3 = bias[n0 + 3];
#pragma unroll
    for (int i = 0; i < 4; ++i) {
        const int m = row0 + ty * 4 + i;
        float4 v = {acc[i][0] + b0, acc[i][1] + b1, acc[i][2] + b2, acc[i][3] + b3};
        *(float4*)(C + (size_t)m * D + n0) = v;
    }
}

// ---------------------------------------------------------------------------
extern "C" void kernel_launch(void* const* d_in, const int* in_sizes, int n_in,
                              void* d_out, int out_size, void* d_ws, size_t ws_size,
                              hipStream_t stream)
{
    const float* x     = (const float*)d_in[0];
    const float* W_qkv = (const float*)d_in[1];
    const float* b_qkv = (const float*)d_in[2];
    const float* W_out = (const float*)d_in[3];
    const float* b_out = (const float*)d_in[4];

    float* out  = (float*)d_out;                      // [B,S,D]
    float* attn = out + (size_t)B * S * D;            // [B,H,S,S]

    float* Q  = (float*)d_ws;                         // [B,H,S,HD]
    float* Kt = Q  + QSZ;
    float* V  = Kt + QSZ;
    float* vt = V  + QSZ;                             // [B,S,H,HD]

    // 1) QKV projection with per-head scatter
    k_qkv<<<dim3(3 * D / 64, (B * S) / 64), 256, 0, stream>>>(x, W_qkv, b_qkv, Q, Kt, V);

    // 2) Scores -> attention region (pre-softmax)
    k_scores<<<dim3(S / 64, S / 64, BH), 256, 0, stream>>>(Q, Kt, attn);

    // 3) Row softmax in place
    k_softmax<<<dim3(BH * S), 256, 0, stream>>>(attn);

    // 4) P @ V -> vt [B,S,D]
    k_pv<<<dim3(S / 64, BH), 256, 0, stream>>>(attn, V, vt);

    // 5) Output projection
    k_out<<<dim3(D / 64, (B * S) / 64), 256, 0, stream>>>(vt, W_out, b_out, out);
}

// Round 2
// 404.021 us; speedup vs baseline: 3.1473x; 3.1473x over previous
//
#include <hip/hip_runtime.h>
#include <cstddef>
#include <cstdint>

typedef __attribute__((ext_vector_type(8))) short short8;   // 8 bf16 (4 VGPR)
typedef __attribute__((ext_vector_type(4))) float f32x4;    // MFMA C/D frag
typedef __attribute__((ext_vector_type(4))) unsigned short us4;

constexpr int BS = 2;     // batch
constexpr int S  = 2048;
constexpr int D  = 1024;
constexpr int H  = 16;
constexpr int HD = 64;
constexpr int BH = BS * H;                  // 32
constexpr float QSCALE = 0.18033688011112042f;  // 0.125 * log2(e)

// f32 -> bf16 round-to-nearest-even
__device__ __forceinline__ unsigned short f2bf(float x) {
    unsigned u = __builtin_bit_cast(unsigned, x);
    u += 0x7fffu + ((u >> 16) & 1u);
    return (unsigned short)(u >> 16);
}

// native 2^x
__device__ __forceinline__ float fexp2(float x) {
    float r; asm("v_exp_f32 %0, %1" : "=v"(r) : "v"(x)); return r;
}

__device__ __forceinline__ f32x4 MFMA(short8 a, short8 b, f32x4 c) {
    return __builtin_amdgcn_mfma_f32_16x16x32_bf16(a, b, c, 0, 0, 0);
}

// ---------------------------------------------------------------------------
// LDS staging: tile [rows][64 bf16] (128 B rows), XOR-swizzled by (row&7)<<4.
// g points at the tile's (0,0); gstride = global row stride in BYTES.
// bytes = rows*128 (constant at call site -> unrolls).
// ---------------------------------------------------------------------------
__device__ __forceinline__ void stage(char* lds, const char* g, int gstride,
                                      int bytes, int tid) {
    for (int f = tid * 16; f < bytes; f += 4096) {
        int row = f >> 7, colb = f & 127;
        short8 v = *(const short8*)(g + (size_t)row * gstride + colb);
        *(short8*)(lds + row * 128 + (colb ^ ((row & 7) << 4))) = v;
    }
}

// swizzled fragment load: 8 contiguous bf16 of LDS row
__device__ __forceinline__ short8 fld(const char* lds, int row, int kb) {
    return *(const short8*)(lds + row * 128 + (kb ^ ((row & 7) << 4)));
}

// ---------------------------------------------------------------------------
// Convert x (f32) -> bf16, straight copy
// ---------------------------------------------------------------------------
__global__ __launch_bounds__(256) void k_cvt(const float* __restrict__ src,
                                             unsigned short* __restrict__ dst,
                                             int n4) {
    int i = blockIdx.x * 256 + threadIdx.x;
    if (i < n4) {
        f32x4 v = ((const f32x4*)src)[i];
        us4 o = {f2bf(v[0]), f2bf(v[1]), f2bf(v[2]), f2bf(v[3])};
        ((us4*)dst)[i] = o;
    }
}

// ---------------------------------------------------------------------------
// Transpose f32 [K][N] -> bf16 [N][K]
// ---------------------------------------------------------------------------
__global__ __launch_bounds__(256) void k_tr(const float* __restrict__ src,
                                            unsigned short* __restrict__ dst,
                                            int K, int N) {
    __shared__ float t[64][65];
    const int k0 = blockIdx.y * 64, n0 = blockIdx.x * 64;
    const int rr = threadIdx.x >> 4, c4 = (threadIdx.x & 15) * 4;
#pragma unroll
    for (int u = 0; u < 4; ++u) {
        int r = rr + u * 16;
        f32x4 v = *(const f32x4*)(src + (size_t)(k0 + r) * N + n0 + c4);
        t[r][c4 + 0] = v[0]; t[r][c4 + 1] = v[1];
        t[r][c4 + 2] = v[2]; t[r][c4 + 3] = v[3];
    }
    __syncthreads();
#pragma unroll
    for (int u = 0; u < 4; ++u) {
        int r = rr + u * 16;
        us4 o = {f2bf(t[c4 + 0][r]), f2bf(t[c4 + 1][r]),
                 f2bf(t[c4 + 2][r]), f2bf(t[c4 + 3][r])};
        *(us4*)(dst + (size_t)(n0 + r) * K + k0 + c4) = o;
    }
}

// ---------------------------------------------------------------------------
// GEMM core: block tile 128(n) x 128(m), K=1024, BK=64, 4 waves (2n x 2m),
// each wave 64x64 via 4x4 16x16 frags.  A = Wt [N][K] bf16, B = Xb [M][K] bf16.
// D^T orientation: frag row index = n-local, col (lane&15) = m-local.
// ---------------------------------------------------------------------------
__device__ __forceinline__ void gemm_core(const char* Ag, const char* Bg,
                                          char* lA, char* lB, int tid,
                                          f32x4 (&acc)[4][4]) {
    const int l = tid & 63, g = l >> 4, li = l & 15;
    const int w = tid >> 6, wn = w >> 1, wm = w & 1;
    for (int k0 = 0; k0 < 1024; k0 += 64) {
        __syncthreads();
        stage(lA, Ag + k0 * 2, 2048, 16384, tid);
        stage(lB, Bg + k0 * 2, 2048, 16384, tid);
        __syncthreads();
#pragma unroll
        for (int kf = 0; kf < 2; ++kf) {
            short8 a[4], b[4];
#pragma unroll
            for (int i = 0; i < 4; ++i) a[i] = fld(lA, wn * 64 + i * 16 + li, kf * 64 + g * 16);
#pragma unroll
            for (int i = 0; i < 4; ++i) b[i] = fld(lB, wm * 64 + i * 16 + li, kf * 64 + g * 16);
#pragma unroll
            for (int i = 0; i < 4; ++i)
#pragma unroll
                for (int j = 0; j < 4; ++j) acc[i][j] = MFMA(a[i], b[j], acc[i][j]);
        }
    }
}

// QKV projection: A = WqT [3072][1024], B = xb [4096][1024]
// Scatter epilogue into Q,K (bf16 [BH][S][HD]) and Vt (bf16 [BH][HD][S]).
// Q gets QSCALE folded in.
__global__ __launch_bounds__(256) void k_qkv(const unsigned short* __restrict__ WqT,
                                             const unsigned short* __restrict__ xb,
                                             const float* __restrict__ bias,
                                             unsigned short* __restrict__ Qb,
                                             unsigned short* __restrict__ Kb,
                                             unsigned short* __restrict__ Vt) {
    __shared__ alignas(16) char lA[16384];
    __shared__ alignas(16) char lB[16384];
    const int tid = threadIdx.x;
    f32x4 acc[4][4] = {};
    const char* Ag = (const char*)(WqT + (size_t)blockIdx.y * 128 * 1024);
    const char* Bg = (const char*)(xb  + (size_t)blockIdx.x * 128 * 1024);
    gemm_core(Ag, Bg, lA, lB, tid, acc);

    const int l = tid & 63, g = l >> 4, li = l & 15;
    const int w = tid >> 6, wn = w >> 1, wm = w & 1;
    const int nBase = blockIdx.y * 128 + wn * 64;
    const int mBase = blockIdx.x * 128 + wm * 64;
#pragma unroll
    for (int i = 0; i < 4; ++i)
#pragma unroll
        for (int j = 0; j < 4; ++j) {
            int n0 = nBase + i * 16 + g * 4;
            int m  = mBase + j * 16 + li;
            int bb = m >> 11, s = m & (S - 1);
            int h = n0 / 192, r2 = n0 % 192, tt = r2 >> 6, d0 = r2 & 63;
            f32x4 v = acc[i][j];
            v[0] += bias[n0]; v[1] += bias[n0 + 1];
            v[2] += bias[n0 + 2]; v[3] += bias[n0 + 3];
            if (tt == 0) { v[0] *= QSCALE; v[1] *= QSCALE; v[2] *= QSCALE; v[3] *= QSCALE; }
            if (tt < 2) {
                unsigned short* dst = (tt ? Kb : Qb) +
                    (((size_t)bb * H + h) * S + s) * HD + d0;
                us4 o = {f2bf(v[0]), f2bf(v[1]), f2bf(v[2]), f2bf(v[3])};
                *(us4*)dst = o;
            } else {
#pragma unroll
                for (int r = 0; r < 4; ++r)
                    Vt[(((size_t)bb * H + h) * HD + d0 + r) * S + s] = f2bf(v[r]);
            }
        }
}

// Output projection: A = WoT [1024][1024], B = vtb [4096][1024], f32 out + bias
__global__ __launch_bounds__(256) void k_out(const unsigned short* __restrict__ WoT,
                                             const unsigned short* __restrict__ vtb,
                                             const float* __restrict__ bias,
                                             float* __restrict__ outp) {
    __shared__ alignas(16) char lA[16384];
    __shared__ alignas(16) char lB[16384];
    const int tid = threadIdx.x;
    f32x4 acc[4][4] = {};
    const char* Ag = (const char*)(WoT + (size_t)blockIdx.y * 128 * 1024);
    const char* Bg = (const char*)(vtb + (size_t)blockIdx.x * 128 * 1024);
    gemm_core(Ag, Bg, lA, lB, tid, acc);

    const int l = tid & 63, g = l >> 4, li = l & 15;
    const int w = tid >> 6, wn = w >> 1, wm = w & 1;
    const int nBase = blockIdx.y * 128 + wn * 64;
    const int mBase = blockIdx.x * 128 + wm * 64;
#pragma unroll
    for (int i = 0; i < 4; ++i)
#pragma unroll
        for (int j = 0; j < 4; ++j) {
            int n0 = nBase + i * 16 + g * 4;
            int m  = mBase + j * 16 + li;
            f32x4 v = acc[i][j];
            const f32x4 b4 = *(const f32x4*)(bias + n0);
            v += b4;
            *(f32x4*)(outp + (size_t)m * D + n0) = v;
        }
}

// ---------------------------------------------------------------------------
// Fused attention: per block (qblock 128, bh), 4 waves x 32 q-rows.
// Pass 1: QK^T (swapped: mfma(K,Q) -> S^T frags), exp2 row-sums.
// Pass 2: recompute, p = exp2(s)*invl, write probs (f32), P->LDS (bf16,
// swizzled, wave-private), PV via mfma(V,P) -> vt^T frags -> vtb bf16.
// ---------------------------------------------------------------------------
__global__ __launch_bounds__(256) void k_attn(const unsigned short* __restrict__ Qb,
                                              const unsigned short* __restrict__ Kb,
                                              const unsigned short* __restrict__ Vt,
                                              float* __restrict__ attn,
                                              unsigned short* __restrict__ vtb) {
    __shared__ alignas(16) char lK[8192];    // [64 kv][64 hd]
    __shared__ alignas(16) char lV[8192];    // [64 d][64 kv]
    __shared__ alignas(16) char lP[16384];   // per-wave [32 q][64 kv] bf16
    const int tid = threadIdx.x;
    const int w = tid >> 6, l = tid & 63, g = l >> 4, li = l & 15;
    const int bh = blockIdx.y;
    const int b = bh >> 4, h = bh & 15;
    const int q0 = blockIdx.x * 128 + w * 32;

    const char* Qg = (const char*)(Qb + (size_t)bh * S * HD);
    const char* Kg = (const char*)(Kb + (size_t)bh * S * HD);
    const char* Vg = (const char*)(Vt + (size_t)bh * HD * S);
    float* attnb = attn + (size_t)bh * S * S;
    char* pb = lP + w * 4096;

    // Q fragments (B-operand): qf x kf, lane: qrow = q0+qf*16+li, k = kf*32+g*8
    short8 qfr[2][2];
#pragma unroll
    for (int qi = 0; qi < 2; ++qi)
#pragma unroll
        for (int kf = 0; kf < 2; ++kf)
            qfr[qi][kf] = *(const short8*)(Qg + (size_t)(q0 + qi * 16 + li) * 128 + kf * 64 + g * 16);

    float run_l[2] = {0.f, 0.f};

    // ---- pass 1: denominators ----
    for (int t = 0; t < 32; ++t) {
        __syncthreads();
        stage(lK, Kg + (size_t)t * 8192, 128, 8192, tid);
        __syncthreads();
        f32x4 sc[4][2] = {};
#pragma unroll
        for (int kf = 0; kf < 2; ++kf) {
            short8 a[4];
#pragma unroll
            for (int i = 0; i < 4; ++i) a[i] = fld(lK, i * 16 + li, kf * 64 + g * 16);
#pragma unroll
            for (int i = 0; i < 4; ++i)
#pragma unroll
                for (int qi = 0; qi < 2; ++qi) sc[i][qi] = MFMA(a[i], qfr[qi][kf], sc[i][qi]);
        }
#pragma unroll
        for (int qi = 0; qi < 2; ++qi) {
            float part = 0.f;
#pragma unroll
            for (int i = 0; i < 4; ++i)
#pragma unroll
                for (int r = 0; r < 4; ++r) part += fexp2(sc[i][qi][r]);
            part += __shfl_xor(part, 16);
            part += __shfl_xor(part, 32);
            run_l[qi] += part;
        }
    }
    const float invl[2] = {1.f / run_l[0], 1.f / run_l[1]};

    // ---- pass 2: probs + PV ----
    f32x4 oacc[4][2] = {};   // [dfrag][qfrag], D[d][q]
    for (int t = 0; t < 32; ++t) {
        __syncthreads();
        stage(lK, Kg + (size_t)t * 8192, 128, 8192, tid);
        stage(lV, Vg + (size_t)t * 128, 4096, 8192, tid);
        __syncthreads();
        f32x4 sc[4][2] = {};
#pragma unroll
        for (int kf = 0; kf < 2; ++kf) {
            short8 a[4];
#pragma unroll
            for (int i = 0; i < 4; ++i) a[i] = fld(lK, i * 16 + li, kf * 64 + g * 16);
#pragma unroll
            for (int i = 0; i < 4; ++i)
#pragma unroll
                for (int qi = 0; qi < 2; ++qi) sc[i][qi] = MFMA(a[i], qfr[qi][kf], sc[i][qi]);
        }
#pragma unroll
        for (int i = 0; i < 4; ++i)
#pragma unroll
            for (int qi = 0; qi < 2; ++qi) {
                f32x4 p;
#pragma unroll
                for (int r = 0; r < 4; ++r) p[r] = fexp2(sc[i][qi][r]) * invl[qi];
                const int qrow = q0 + qi * 16 + li;
                *(f32x4*)(attnb + (size_t)qrow * S + t * 64 + i * 16 + g * 4) = p;
                const int row = qi * 16 + li;
                us4 o = {f2bf(p[0]), f2bf(p[1]), f2bf(p[2]), f2bf(p[3])};
                *(us4*)(pb + row * 128 + ((i * 32 + g * 8) ^ ((row & 7) << 4))) = o;
            }
        // PV: D[d][q] += V^T-frag x P-frag
#pragma unroll
        for (int kvf = 0; kvf < 2; ++kvf) {
            short8 pa[2], vb[4];
#pragma unroll
            for (int qi = 0; qi < 2; ++qi) pa[qi] = fld(pb, qi * 16 + li, kvf * 64 + g * 16);
#pragma unroll
            for (int df = 0; df < 4; ++df) vb[df] = fld(lV, df * 16 + li, kvf * 64 + g * 16);
#pragma unroll
            for (int df = 0; df < 4; ++df)
#pragma unroll
                for (int qi = 0; qi < 2; ++qi) oacc[df][qi] = MFMA(vb[df], pa[qi], oacc[df][qi]);
        }
    }

    // vtb [B*S][H*HD] bf16: lane holds fixed q (li), 4 consecutive d (rows)
#pragma unroll
    for (int df = 0; df < 4; ++df)
#pragma unroll
        for (int qi = 0; qi < 2; ++qi) {
            const int qrow = q0 + qi * 16 + li;
            const size_t m = (size_t)b * S + qrow;
            const int d0 = df * 16 + g * 4;
            us4 o = {f2bf(oacc[df][qi][0]), f2bf(oacc[df][qi][1]),
                     f2bf(oacc[df][qi][2]), f2bf(oacc[df][qi][3])};
            *(us4*)(vtb + m * D + h * HD + d0) = o;
        }
}

// ---------------------------------------------------------------------------
extern "C" void kernel_launch(void* const* d_in, const int* in_sizes, int n_in,
                              void* d_out, int out_size, void* d_ws, size_t ws_size,
                              hipStream_t stream) {
    const float* x     = (const float*)d_in[0];
    const float* W_qkv = (const float*)d_in[1];
    const float* b_qkv = (const float*)d_in[2];
    const float* W_out = (const float*)d_in[3];
    const float* b_out = (const float*)d_in[4];

    float* out  = (float*)d_out;                    // [B,S,D] f32
    float* attn = out + (size_t)BS * S * D;         // [B,H,S,S] f32

    char* ws = (char*)d_ws;
    unsigned short* xb  = (unsigned short*)(ws);                    // [4096][1024]
    unsigned short* wqT = (unsigned short*)(ws + 8388608);          // [3072][1024]
    unsigned short* woT = (unsigned short*)(ws + 14680064);         // [1024][1024]
    unsigned short* Qb  = (unsigned short*)(ws + 16777216);         // [BH][S][HD]
    unsigned short* Kb  = (unsigned short*)(ws + 25165824);         // [BH][S][HD]
    unsigned short* Vt  = (unsigned short*)(ws + 33554432);         // [BH][HD][S]
    unsigned short* vtb = (unsigned short*)(ws + 41943040);         // [4096][1024]

    k_cvt<<<4096, 256, 0, stream>>>(x, xb, (BS * S * D) / 4);
    k_tr<<<dim3(48, 16), 256, 0, stream>>>(W_qkv, wqT, D, 3 * D);
    k_tr<<<dim3(16, 16), 256, 0, stream>>>(W_out, woT, D, D);

    k_qkv<<<dim3(32, 24), 256, 0, stream>>>(wqT, xb, b_qkv, Qb, Kb, Vt);
    k_attn<<<dim3(16, 32), 256, 0, stream>>>(Qb, Kb, Vt, attn, vtb);
    k_out<<<dim3(32, 8), 256, 0, stream>>>(woT, vtb, b_out, out);
}

// Round 3
// 365.542 us; speedup vs baseline: 3.4786x; 1.1053x over previous
//
#include <hip/hip_runtime.h>
#include <cstddef>
#include <cstdint>

typedef __attribute__((ext_vector_type(8))) short short8;   // 8 bf16 (4 VGPR)
typedef __attribute__((ext_vector_type(4))) float f32x4;    // MFMA C/D frag
typedef __attribute__((ext_vector_type(4))) unsigned short us4;

constexpr int BS = 2;     // batch
constexpr int S  = 2048;
constexpr int D  = 1024;
constexpr int H  = 16;
constexpr int HD = 64;
constexpr int BH = BS * H;                  // 32
constexpr float QSCALE = 0.18033688011112042f;  // 0.125 * log2(e)

// f32 -> bf16 round-to-nearest-even
__device__ __forceinline__ unsigned short f2bf(float x) {
    unsigned u = __builtin_bit_cast(unsigned, x);
    u += 0x7fffu + ((u >> 16) & 1u);
    return (unsigned short)(u >> 16);
}

// native 2^x
__device__ __forceinline__ float fexp2(float x) {
    float r; asm("v_exp_f32 %0, %1" : "=v"(r) : "v"(x)); return r;
}

__device__ __forceinline__ f32x4 MFMA(short8 a, short8 b, f32x4 c) {
    return __builtin_amdgcn_mfma_f32_16x16x32_bf16(a, b, c, 0, 0, 0);
}

// ---------------------------------------------------------------------------
// LDS staging for the projection GEMMs: tile [rows][64 bf16] (128 B rows),
// XOR-swizzled by (row&7)<<4.
// ---------------------------------------------------------------------------
__device__ __forceinline__ void stage(char* lds, const char* g, int gstride,
                                      int bytes, int tid) {
    for (int f = tid * 16; f < bytes; f += 4096) {
        int row = f >> 7, colb = f & 127;
        short8 v = *(const short8*)(g + (size_t)row * gstride + colb);
        *(short8*)(lds + row * 128 + (colb ^ ((row & 7) << 4))) = v;
    }
}

__device__ __forceinline__ short8 fld(const char* lds, int row, int kb) {
    return *(const short8*)(lds + row * 128 + (kb ^ ((row & 7) << 4)));
}

// ---------------------------------------------------------------------------
// Convert x (f32) -> bf16
// ---------------------------------------------------------------------------
__global__ __launch_bounds__(256) void k_cvt(const float* __restrict__ src,
                                             unsigned short* __restrict__ dst,
                                             int n4) {
    int i = blockIdx.x * 256 + threadIdx.x;
    if (i < n4) {
        f32x4 v = ((const f32x4*)src)[i];
        us4 o = {f2bf(v[0]), f2bf(v[1]), f2bf(v[2]), f2bf(v[3])};
        ((us4*)dst)[i] = o;
    }
}

// ---------------------------------------------------------------------------
// Transpose f32 [K][N] -> bf16 [N][K]
// ---------------------------------------------------------------------------
__global__ __launch_bounds__(256) void k_tr(const float* __restrict__ src,
                                            unsigned short* __restrict__ dst,
                                            int K, int N) {
    __shared__ float t[64][65];
    const int k0 = blockIdx.y * 64, n0 = blockIdx.x * 64;
    const int rr = threadIdx.x >> 4, c4 = (threadIdx.x & 15) * 4;
#pragma unroll
    for (int u = 0; u < 4; ++u) {
        int r = rr + u * 16;
        f32x4 v = *(const f32x4*)(src + (size_t)(k0 + r) * N + n0 + c4);
        t[r][c4 + 0] = v[0]; t[r][c4 + 1] = v[1];
        t[r][c4 + 2] = v[2]; t[r][c4 + 3] = v[3];
    }
    __syncthreads();
#pragma unroll
    for (int u = 0; u < 4; ++u) {
        int r = rr + u * 16;
        us4 o = {f2bf(t[c4 + 0][r]), f2bf(t[c4 + 1][r]),
                 f2bf(t[c4 + 2][r]), f2bf(t[c4 + 3][r])};
        *(us4*)(dst + (size_t)(n0 + r) * K + k0 + c4) = o;
    }
}

// ---------------------------------------------------------------------------
// GEMM core: block tile 128(n) x 128(m), K=1024, BK=64, 4 waves (2n x 2m).
// acc[i][j][r] = C[token m = mBase + j*16 + li][feature n = nBase + i*16 + g*4 + r]
// ---------------------------------------------------------------------------
__device__ __forceinline__ void gemm_core(const char* Ag, const char* Bg,
                                          char* lA, char* lB, int tid,
                                          f32x4 (&acc)[4][4]) {
    const int l = tid & 63, g = l >> 4, li = l & 15;
    const int w = tid >> 6, wn = w >> 1, wm = w & 1;
    for (int k0 = 0; k0 < 1024; k0 += 64) {
        __syncthreads();
        stage(lA, Ag + k0 * 2, 2048, 16384, tid);
        stage(lB, Bg + k0 * 2, 2048, 16384, tid);
        __syncthreads();
#pragma unroll
        for (int kf = 0; kf < 2; ++kf) {
            short8 a[4], b[4];
#pragma unroll
            for (int i = 0; i < 4; ++i) a[i] = fld(lA, wn * 64 + i * 16 + li, kf * 64 + g * 16);
#pragma unroll
            for (int i = 0; i < 4; ++i) b[i] = fld(lB, wm * 64 + i * 16 + li, kf * 64 + g * 16);
#pragma unroll
            for (int i = 0; i < 4; ++i)
#pragma unroll
                for (int j = 0; j < 4; ++j) acc[i][j] = MFMA(a[i], b[j], acc[i][j]);
        }
    }
}

// ---------------------------------------------------------------------------
// QKV projection: A = WqT [3072][1024], B = xb [4096][1024].
// Epilogue scatters into MFMA-fragment layouts:
//   Qf: [bh][qt=s/16][kf=d/32][lane=g*16+(s%16)][j=d%8]   (QSCALE folded)
//   Kf: [bh][t=s/64][kf=d/32][i=(s/16)%4][lane=g*16+(s%16)][j=d%8]
//   Vf: [bh][t][kvf=(s/32)%2][df=d/16][lane=gv*16+(d%16)][j=s%8]
// where g=(d%32)/8, gv=(s%32)/8.
// ---------------------------------------------------------------------------
__global__ __launch_bounds__(256) void k_qkv(const unsigned short* __restrict__ WqT,
                                             const unsigned short* __restrict__ xb,
                                             const float* __restrict__ bias,
                                             unsigned short* __restrict__ Qf,
                                             unsigned short* __restrict__ Kf,
                                             unsigned short* __restrict__ Vf) {
    __shared__ alignas(16) char lA[16384];
    __shared__ alignas(16) char lB[16384];
    const int tid = threadIdx.x;
    f32x4 acc[4][4] = {};
    const char* Ag = (const char*)(WqT + (size_t)blockIdx.y * 128 * 1024);
    const char* Bg = (const char*)(xb  + (size_t)blockIdx.x * 128 * 1024);
    gemm_core(Ag, Bg, lA, lB, tid, acc);

    const int l = tid & 63, g = l >> 4, li = l & 15;
    const int w = tid >> 6, wn = w >> 1, wm = w & 1;
    const int nBase = blockIdx.y * 128 + wn * 64;
    const int mBase = blockIdx.x * 128 + wm * 64;
#pragma unroll
    for (int i = 0; i < 4; ++i)
#pragma unroll
        for (int j = 0; j < 4; ++j) {
            const int n0 = nBase + i * 16 + g * 4;
            const int m  = mBase + j * 16 + li;
            const int bb = m >> 11, s = m & (S - 1);
            const int h = n0 / 192, r2 = n0 % 192, tt = r2 >> 6, d0 = r2 & 63;
            const int bh_ = bb * H + h;
            f32x4 v = acc[i][j];
            const f32x4 b4 = *(const f32x4*)(bias + n0);
            v += b4;
            if (tt == 0) {
                v[0] *= QSCALE; v[1] *= QSCALE; v[2] *= QSCALE; v[3] *= QSCALE;
                us4 o = {f2bf(v[0]), f2bf(v[1]), f2bf(v[2]), f2bf(v[3])};
                size_t e = (((size_t)bh_ * 128 + (s >> 4)) * 2 + (d0 >> 5)) * 512
                         + (((d0 & 31) >> 3) * 16 + (s & 15)) * 8 + (d0 & 7);
                *(us4*)(Qf + e) = o;
            } else if (tt == 1) {
                us4 o = {f2bf(v[0]), f2bf(v[1]), f2bf(v[2]), f2bf(v[3])};
                size_t e = ((((size_t)bh_ * 32 + (s >> 6)) * 2 + (d0 >> 5)) * 4
                            + ((s >> 4) & 3)) * 512
                         + (((d0 & 31) >> 3) * 16 + (s & 15)) * 8 + (d0 & 7);
                *(us4*)(Kf + e) = o;
            } else {
                size_t vbase = ((((size_t)bh_ * 32 + (s >> 6)) * 2 + ((s >> 5) & 1)) * 4
                                + (d0 >> 4)) * 512
                             + ((s >> 3) & 3) * 128 + (s & 7);
#pragma unroll
                for (int r = 0; r < 4; ++r)
                    Vf[vbase + ((d0 & 15) + r) * 8] = f2bf(v[r]);
            }
        }
}

// ---------------------------------------------------------------------------
// Output projection: A = WoT [1024][1024], B = vtb [4096][1024], f32 out + bias
// ---------------------------------------------------------------------------
__global__ __launch_bounds__(256) void k_out(const unsigned short* __restrict__ WoT,
                                             const unsigned short* __restrict__ vtb,
                                             const float* __restrict__ bias,
                                             float* __restrict__ outp) {
    __shared__ alignas(16) char lA[16384];
    __shared__ alignas(16) char lB[16384];
    const int tid = threadIdx.x;
    f32x4 acc[4][4] = {};
    const char* Ag = (const char*)(WoT + (size_t)blockIdx.y * 128 * 1024);
    const char* Bg = (const char*)(vtb + (size_t)blockIdx.x * 128 * 1024);
    gemm_core(Ag, Bg, lA, lB, tid, acc);

    const int l = tid & 63, g = l >> 4, li = l & 15;
    const int w = tid >> 6, wn = w >> 1, wm = w & 1;
    const int nBase = blockIdx.y * 128 + wn * 64;
    const int mBase = blockIdx.x * 128 + wm * 64;
#pragma unroll
    for (int i = 0; i < 4; ++i)
#pragma unroll
        for (int j = 0; j < 4; ++j) {
            const int n0 = nBase + i * 16 + g * 4;
            const int m  = mBase + j * 16 + li;
            f32x4 v = acc[i][j];
            const f32x4 b4 = *(const f32x4*)(bias + n0);
            v += b4;
            *(f32x4*)(outp + (size_t)m * D + n0) = v;
        }
}

// ---------------------------------------------------------------------------
// Fused attention, barrier-free. Per block: 4 independent waves x 32 q-rows.
// All K/V/Q fragment loads straight from global (L2-resident, fully
// coalesced). Only wave-private P round-trips through LDS (swizzled).
// Pass 1: denominators. Pass 2: probs (f32 out) + PV accumulation.
// ---------------------------------------------------------------------------
__global__ __launch_bounds__(256) void k_attn(const unsigned short* __restrict__ Qf,
                                              const unsigned short* __restrict__ Kf,
                                              const unsigned short* __restrict__ Vf,
                                              float* __restrict__ attn,
                                              unsigned short* __restrict__ vtb) {
    __shared__ alignas(16) char lP[16384];
    const int tid = threadIdx.x;
    const int w = tid >> 6, l = tid & 63, g = l >> 4, li = l & 15;
    const int bh = blockIdx.y, b = bh >> 4, h = bh & 15;
    const int q0 = blockIdx.x * 128 + w * 32;
    char* pb = lP + w * 4096;

    const short8* Q8 = (const short8*)Qf;
    const short8* K8 = (const short8*)Kf;
    const short8* V8 = (const short8*)Vf;
    float* attnb = attn + (size_t)bh * S * S;

    // Q fragments (B-operand): lane holds Q[q=qt*16+li][k=kf*32+g*8+j]
    short8 qfr[2][2];
#pragma unroll
    for (int qi = 0; qi < 2; ++qi)
#pragma unroll
        for (int kf = 0; kf < 2; ++kf)
            qfr[qi][kf] = Q8[(((size_t)bh * 128 + (q0 >> 4) + qi) * 2 + kf) * 64 + l];

    // ---- pass 1: denominators ----
    float run_l[2] = {0.f, 0.f};
    for (int t = 0; t < 32; ++t) {
        f32x4 sc[4][2] = {};
#pragma unroll
        for (int kf = 0; kf < 2; ++kf) {
            short8 a[4];
#pragma unroll
            for (int i = 0; i < 4; ++i)
                a[i] = K8[((((size_t)bh * 32 + t) * 2 + kf) * 4 + i) * 64 + l];
            __builtin_amdgcn_s_setprio(1);
#pragma unroll
            for (int i = 0; i < 4; ++i)
#pragma unroll
                for (int qi = 0; qi < 2; ++qi)
                    sc[i][qi] = MFMA(a[i], qfr[qi][kf], sc[i][qi]);
            __builtin_amdgcn_s_setprio(0);
        }
#pragma unroll
        for (int qi = 0; qi < 2; ++qi) {
            float part = 0.f;
#pragma unroll
            for (int i = 0; i < 4; ++i)
#pragma unroll
                for (int r = 0; r < 4; ++r) part += fexp2(sc[i][qi][r]);
            part += __shfl_xor(part, 16);
            part += __shfl_xor(part, 32);
            run_l[qi] += part;
        }
    }
    const float invl[2] = {1.f / run_l[0], 1.f / run_l[1]};

    // ---- pass 2: probs + PV ----
    f32x4 oacc[4][2] = {};   // [dfrag][qfrag], D[d][q]
    for (int t = 0; t < 32; ++t) {
        f32x4 sc[4][2] = {};
#pragma unroll
        for (int kf = 0; kf < 2; ++kf) {
            short8 a[4];
#pragma unroll
            for (int i = 0; i < 4; ++i)
                a[i] = K8[((((size_t)bh * 32 + t) * 2 + kf) * 4 + i) * 64 + l];
            __builtin_amdgcn_s_setprio(1);
#pragma unroll
            for (int i = 0; i < 4; ++i)
#pragma unroll
                for (int qi = 0; qi < 2; ++qi)
                    sc[i][qi] = MFMA(a[i], qfr[qi][kf], sc[i][qi]);
            __builtin_amdgcn_s_setprio(0);
        }
#pragma unroll
        for (int i = 0; i < 4; ++i)
#pragma unroll
            for (int qi = 0; qi < 2; ++qi) {
                f32x4 p;
#pragma unroll
                for (int r = 0; r < 4; ++r) p[r] = fexp2(sc[i][qi][r]) * invl[qi];
                const int qrow = q0 + qi * 16 + li;
                *(f32x4*)(attnb + (size_t)qrow * S + t * 64 + i * 16 + g * 4) = p;
                const int row = qi * 16 + li;
                us4 o = {f2bf(p[0]), f2bf(p[1]), f2bf(p[2]), f2bf(p[3])};
                *(us4*)(pb + row * 128 + ((i * 32 + g * 8) ^ ((row & 7) << 4))) = o;
            }
        // PV: D[d][q] += V^T-frag x P-frag
#pragma unroll
        for (int kvf = 0; kvf < 2; ++kvf) {
            short8 pa[2], vb[4];
#pragma unroll
            for (int qi = 0; qi < 2; ++qi)
                pa[qi] = fld(pb, qi * 16 + li, kvf * 64 + g * 16);
#pragma unroll
            for (int df = 0; df < 4; ++df)
                vb[df] = V8[((((size_t)bh * 32 + t) * 2 + kvf) * 4 + df) * 64 + l];
            __builtin_amdgcn_s_setprio(1);
#pragma unroll
            for (int df = 0; df < 4; ++df)
#pragma unroll
                for (int qi = 0; qi < 2; ++qi)
                    oacc[df][qi] = MFMA(vb[df], pa[qi], oacc[df][qi]);
            __builtin_amdgcn_s_setprio(0);
        }
    }

    // vtb [B*S][H*HD] bf16
#pragma unroll
    for (int df = 0; df < 4; ++df)
#pragma unroll
        for (int qi = 0; qi < 2; ++qi) {
            const int qrow = q0 + qi * 16 + li;
            const size_t m = (size_t)b * S + qrow;
            const int d0 = df * 16 + g * 4;
            us4 o = {f2bf(oacc[df][qi][0]), f2bf(oacc[df][qi][1]),
                     f2bf(oacc[df][qi][2]), f2bf(oacc[df][qi][3])};
            *(us4*)(vtb + m * D + h * HD + d0) = o;
        }
}

// ---------------------------------------------------------------------------
extern "C" void kernel_launch(void* const* d_in, const int* in_sizes, int n_in,
                              void* d_out, int out_size, void* d_ws, size_t ws_size,
                              hipStream_t stream) {
    const float* x     = (const float*)d_in[0];
    const float* W_qkv = (const float*)d_in[1];
    const float* b_qkv = (const float*)d_in[2];
    const float* W_out = (const float*)d_in[3];
    const float* b_out = (const float*)d_in[4];

    float* out  = (float*)d_out;                    // [B,S,D] f32
    float* attn = out + (size_t)BS * S * D;         // [B,H,S,S] f32

    char* ws = (char*)d_ws;
    unsigned short* xb  = (unsigned short*)(ws);                    // [4096][1024]
    unsigned short* wqT = (unsigned short*)(ws + 8388608);          // [3072][1024]
    unsigned short* woT = (unsigned short*)(ws + 14680064);         // [1024][1024]
    unsigned short* Qf  = (unsigned short*)(ws + 16777216);         // frag layout
    unsigned short* Kf  = (unsigned short*)(ws + 25165824);         // frag layout
    unsigned short* Vf  = (unsigned short*)(ws + 33554432);         // frag layout
    unsigned short* vtb = (unsigned short*)(ws + 41943040);         // [4096][1024]

    k_cvt<<<4096, 256, 0, stream>>>(x, xb, (BS * S * D) / 4);
    k_tr<<<dim3(48, 16), 256, 0, stream>>>(W_qkv, wqT, D, 3 * D);
    k_tr<<<dim3(16, 16), 256, 0, stream>>>(W_out, woT, D, D);

    k_qkv<<<dim3(32, 24), 256, 0, stream>>>(wqT, xb, b_qkv, Qf, Kf, Vf);
    k_attn<<<dim3(16, 32), 256, 0, stream>>>(Qf, Kf, Vf, attn, vtb);
    k_out<<<dim3(32, 8), 256, 0, stream>>>(woT, vtb, b_out, out);
}

// Round 4
// 325.166 us; speedup vs baseline: 3.9106x; 1.1242x over previous
//
#include <hip/hip_runtime.h>
#include <hip/hip_bf16.h>
#include <cstddef>
#include <cstdint>

typedef __attribute__((ext_vector_type(8))) short short8;   // 8 bf16 (4 VGPR)
typedef __attribute__((ext_vector_type(4))) float f32x4;    // MFMA C/D frag
typedef __attribute__((ext_vector_type(4))) unsigned short us4;

constexpr int BS = 2;     // batch
constexpr int S  = 2048;
constexpr int D  = 1024;
constexpr int H  = 16;
constexpr int HD = 64;
constexpr int BH = BS * H;                  // 32
constexpr float QSCALE = 0.18033688011112042f;  // 0.125 * log2(e)

// f32 -> bf16 round-to-nearest-even (scalar)
__device__ __forceinline__ unsigned short f2bf(float x) {
    unsigned u = __builtin_bit_cast(unsigned, x);
    u += 0x7fffu + ((u >> 16) & 1u);
    return (unsigned short)(u >> 16);
}

// packed f32 pair -> 2 bf16 in one u32 (lo = a, hi = b)
__device__ __forceinline__ unsigned pkbf(float a, float b) {
    unsigned r;
    asm("v_cvt_pk_bf16_f32 %0, %1, %2" : "=v"(r) : "v"(a), "v"(b));
    return r;
}

// native 2^x
__device__ __forceinline__ float fexp2(float x) {
    float r; asm("v_exp_f32 %0, %1" : "=v"(r) : "v"(x)); return r;
}

__device__ __forceinline__ f32x4 MFMA(short8 a, short8 b, f32x4 c) {
    return __builtin_amdgcn_mfma_f32_16x16x32_bf16(a, b, c, 0, 0, 0);
}

// ---------------------------------------------------------------------------
// LDS staging for projection GEMMs: tile [rows][64 bf16] (128 B rows),
// XOR-swizzled by (row&7)<<4.
// ---------------------------------------------------------------------------
__device__ __forceinline__ void stage(char* lds, const char* g, int gstride,
                                      int bytes, int tid) {
    for (int f = tid * 16; f < bytes; f += 4096) {
        int row = f >> 7, colb = f & 127;
        short8 v = *(const short8*)(g + (size_t)row * gstride + colb);
        *(short8*)(lds + row * 128 + (colb ^ ((row & 7) << 4))) = v;
    }
}

__device__ __forceinline__ short8 fld(const char* lds, int row, int kb) {
    return *(const short8*)(lds + row * 128 + (kb ^ ((row & 7) << 4)));
}

// ---------------------------------------------------------------------------
// Convert x (f32) -> bf16
// ---------------------------------------------------------------------------
__global__ __launch_bounds__(256) void k_cvt(const float* __restrict__ src,
                                             unsigned short* __restrict__ dst,
                                             int n4) {
    int i = blockIdx.x * 256 + threadIdx.x;
    if (i < n4) {
        f32x4 v = ((const f32x4*)src)[i];
        us4 o = {f2bf(v[0]), f2bf(v[1]), f2bf(v[2]), f2bf(v[3])};
        ((us4*)dst)[i] = o;
    }
}

// ---------------------------------------------------------------------------
// Transpose f32 [K][N] -> bf16 [N][K]
// ---------------------------------------------------------------------------
__global__ __launch_bounds__(256) void k_tr(const float* __restrict__ src,
                                            unsigned short* __restrict__ dst,
                                            int K, int N) {
    __shared__ float t[64][65];
    const int k0 = blockIdx.y * 64, n0 = blockIdx.x * 64;
    const int rr = threadIdx.x >> 4, c4 = (threadIdx.x & 15) * 4;
#pragma unroll
    for (int u = 0; u < 4; ++u) {
        int r = rr + u * 16;
        f32x4 v = *(const f32x4*)(src + (size_t)(k0 + r) * N + n0 + c4);
        t[r][c4 + 0] = v[0]; t[r][c4 + 1] = v[1];
        t[r][c4 + 2] = v[2]; t[r][c4 + 3] = v[3];
    }
    __syncthreads();
#pragma unroll
    for (int u = 0; u < 4; ++u) {
        int r = rr + u * 16;
        us4 o = {f2bf(t[c4 + 0][r]), f2bf(t[c4 + 1][r]),
                 f2bf(t[c4 + 2][r]), f2bf(t[c4 + 3][r])};
        *(us4*)(dst + (size_t)(n0 + r) * K + k0 + c4) = o;
    }
}

// ---------------------------------------------------------------------------
// GEMM core: block tile 128(n) x 128(m), K=1024, BK=64, 4 waves (2n x 2m).
// acc[i][j][r] = C[token m = mBase + j*16 + li][feature n = nBase + i*16 + g*4 + r]
// ---------------------------------------------------------------------------
__device__ __forceinline__ void gemm_core(const char* Ag, const char* Bg,
                                          char* lA, char* lB, int tid,
                                          f32x4 (&acc)[4][4]) {
    const int l = tid & 63, g = l >> 4, li = l & 15;
    const int w = tid >> 6, wn = w >> 1, wm = w & 1;
    for (int k0 = 0; k0 < 1024; k0 += 64) {
        __syncthreads();
        stage(lA, Ag + k0 * 2, 2048, 16384, tid);
        stage(lB, Bg + k0 * 2, 2048, 16384, tid);
        __syncthreads();
#pragma unroll
        for (int kf = 0; kf < 2; ++kf) {
            short8 a[4], b[4];
#pragma unroll
            for (int i = 0; i < 4; ++i) a[i] = fld(lA, wn * 64 + i * 16 + li, kf * 64 + g * 16);
#pragma unroll
            for (int i = 0; i < 4; ++i) b[i] = fld(lB, wm * 64 + i * 16 + li, kf * 64 + g * 16);
#pragma unroll
            for (int i = 0; i < 4; ++i)
#pragma unroll
                for (int j = 0; j < 4; ++j) acc[i][j] = MFMA(a[i], b[j], acc[i][j]);
        }
    }
}

// ---------------------------------------------------------------------------
// QKV projection: A = WqT [3072][1024], B = xb [4096][1024].
// Epilogue scatters into MFMA-fragment layouts (see round-3 comments).
// ---------------------------------------------------------------------------
__global__ __launch_bounds__(256) void k_qkv(const unsigned short* __restrict__ WqT,
                                             const unsigned short* __restrict__ xb,
                                             const float* __restrict__ bias,
                                             unsigned short* __restrict__ Qf,
                                             unsigned short* __restrict__ Kf,
                                             unsigned short* __restrict__ Vf) {
    __shared__ alignas(16) char lA[16384];
    __shared__ alignas(16) char lB[16384];
    const int tid = threadIdx.x;
    f32x4 acc[4][4] = {};
    const char* Ag = (const char*)(WqT + (size_t)blockIdx.y * 128 * 1024);
    const char* Bg = (const char*)(xb  + (size_t)blockIdx.x * 128 * 1024);
    gemm_core(Ag, Bg, lA, lB, tid, acc);

    const int l = tid & 63, g = l >> 4, li = l & 15;
    const int w = tid >> 6, wn = w >> 1, wm = w & 1;
    const int nBase = blockIdx.y * 128 + wn * 64;
    const int mBase = blockIdx.x * 128 + wm * 64;
#pragma unroll
    for (int i = 0; i < 4; ++i)
#pragma unroll
        for (int j = 0; j < 4; ++j) {
            const int n0 = nBase + i * 16 + g * 4;
            const int m  = mBase + j * 16 + li;
            const int bb = m >> 11, s = m & (S - 1);
            const int h = n0 / 192, r2 = n0 % 192, tt = r2 >> 6, d0 = r2 & 63;
            const int bh_ = bb * H + h;
            f32x4 v = acc[i][j];
            const f32x4 b4 = *(const f32x4*)(bias + n0);
            v += b4;
            if (tt == 0) {
                v[0] *= QSCALE; v[1] *= QSCALE; v[2] *= QSCALE; v[3] *= QSCALE;
                us4 o = {f2bf(v[0]), f2bf(v[1]), f2bf(v[2]), f2bf(v[3])};
                size_t e = (((size_t)bh_ * 128 + (s >> 4)) * 2 + (d0 >> 5)) * 512
                         + (((d0 & 31) >> 3) * 16 + (s & 15)) * 8 + (d0 & 7);
                *(us4*)(Qf + e) = o;
            } else if (tt == 1) {
                us4 o = {f2bf(v[0]), f2bf(v[1]), f2bf(v[2]), f2bf(v[3])};
                size_t e = ((((size_t)bh_ * 32 + (s >> 6)) * 2 + (d0 >> 5)) * 4
                            + ((s >> 4) & 3)) * 512
                         + (((d0 & 31) >> 3) * 16 + (s & 15)) * 8 + (d0 & 7);
                *(us4*)(Kf + e) = o;
            } else {
                size_t vbase = ((((size_t)bh_ * 32 + (s >> 6)) * 2 + ((s >> 5) & 1)) * 4
                                + (d0 >> 4)) * 512
                             + ((s >> 3) & 3) * 128 + (s & 7);
#pragma unroll
                for (int r = 0; r < 4; ++r)
                    Vf[vbase + ((d0 & 15) + r) * 8] = f2bf(v[r]);
            }
        }
}

// ---------------------------------------------------------------------------
// Output projection: A = WoT [1024][1024], B = vtb [4096][1024], f32 out + bias
// ---------------------------------------------------------------------------
__global__ __launch_bounds__(256) void k_out(const unsigned short* __restrict__ WoT,
                                             const unsigned short* __restrict__ vtb,
                                             const float* __restrict__ bias,
                                             float* __restrict__ outp) {
    __shared__ alignas(16) char lA[16384];
    __shared__ alignas(16) char lB[16384];
    const int tid = threadIdx.x;
    f32x4 acc[4][4] = {};
    const char* Ag = (const char*)(WoT + (size_t)blockIdx.y * 128 * 1024);
    const char* Bg = (const char*)(vtb + (size_t)blockIdx.x * 128 * 1024);
    gemm_core(Ag, Bg, lA, lB, tid, acc);

    const int l = tid & 63, g = l >> 4, li = l & 15;
    const int w = tid >> 6, wn = w >> 1, wm = w & 1;
    const int nBase = blockIdx.y * 128 + wn * 64;
    const int mBase = blockIdx.x * 128 + wm * 64;
#pragma unroll
    for (int i = 0; i < 4; ++i)
#pragma unroll
        for (int j = 0; j < 4; ++j) {
            const int n0 = nBase + i * 16 + g * 4;
            const int m  = mBase + j * 16 + li;
            f32x4 v = acc[i][j];
            const f32x4 b4 = *(const f32x4*)(bias + n0);
            v += b4;
            *(f32x4*)(outp + (size_t)m * D + n0) = v;
        }
}

// ---------------------------------------------------------------------------
// Fused attention helpers
// ---------------------------------------------------------------------------
__device__ __forceinline__ void ldfr(short8 (&b)[8], const short8* base, int l) {
#pragma unroll
    for (int f = 0; f < 8; ++f) b[f] = base[f * 64 + l];
}

__device__ __forceinline__ void qk_mfma(const short8 (&kb)[8],
                                        const short8 (&qfr)[2][2],
                                        f32x4 (&sc)[4][2]) {
    __builtin_amdgcn_s_setprio(1);
#pragma unroll
    for (int kf = 0; kf < 2; ++kf)
#pragma unroll
        for (int i = 0; i < 4; ++i)
#pragma unroll
            for (int qi = 0; qi < 2; ++qi)
                sc[i][qi] = MFMA(kb[kf * 4 + i], qfr[qi][kf], sc[i][qi]);
    __builtin_amdgcn_s_setprio(0);
}

__device__ __forceinline__ void expsum(const f32x4 (&sc)[4][2], float (&run)[2]) {
#pragma unroll
    for (int qi = 0; qi < 2; ++qi) {
        float part = 0.f;
#pragma unroll
        for (int i = 0; i < 4; ++i)
#pragma unroll
            for (int r = 0; r < 4; ++r) part += fexp2(sc[i][qi][r]);
        part += __shfl_xor(part, 16);
        part += __shfl_xor(part, 32);
        run[qi] += part;
    }
}

__device__ __forceinline__ void p2tile(int t, const short8 (&kb)[8],
                                       const short8 (&vb)[8],
                                       const short8 (&qfr)[2][2],
                                       const float (&invl)[2],
                                       float* __restrict__ attnb, char* pb,
                                       f32x4 (&oacc)[4][2],
                                       int q0, int g, int li) {
    f32x4 sc[4][2] = {};
    qk_mfma(kb, qfr, sc);
#pragma unroll
    for (int i = 0; i < 4; ++i)
#pragma unroll
        for (int qi = 0; qi < 2; ++qi) {
            f32x4 p;
#pragma unroll
            for (int r = 0; r < 4; ++r) p[r] = fexp2(sc[i][qi][r]) * invl[qi];
            const int qrow = q0 + qi * 16 + li;
            *(f32x4*)(attnb + (size_t)qrow * S + t * 64 + i * 16 + g * 4) = p;
            const int row = qi * 16 + li;
            uint2 o = {pkbf(p[0], p[1]), pkbf(p[2], p[3])};
            *(uint2*)(pb + row * 128 + ((i * 32 + g * 8) ^ ((row & 7) << 4))) = o;
        }
    // PV: D[d][q] += V^T-frag x P-frag
    short8 pa[2][2];
#pragma unroll
    for (int kvf = 0; kvf < 2; ++kvf)
#pragma unroll
        for (int qi = 0; qi < 2; ++qi)
            pa[kvf][qi] = fld(pb, qi * 16 + li, kvf * 64 + g * 16);
    __builtin_amdgcn_s_setprio(1);
#pragma unroll
    for (int kvf = 0; kvf < 2; ++kvf)
#pragma unroll
        for (int df = 0; df < 4; ++df)
#pragma unroll
            for (int qi = 0; qi < 2; ++qi)
                oacc[df][qi] = MFMA(vb[kvf * 4 + df], pa[kvf][qi], oacc[df][qi]);
    __builtin_amdgcn_s_setprio(0);
}

// ---------------------------------------------------------------------------
// Fused attention, barrier-free, K register-double-buffered, V issued early.
// ---------------------------------------------------------------------------
__global__ __launch_bounds__(256, 2) void k_attn(const unsigned short* __restrict__ Qf,
                                                 const unsigned short* __restrict__ Kf,
                                                 const unsigned short* __restrict__ Vf,
                                                 float* __restrict__ attn,
                                                 unsigned short* __restrict__ vtb) {
    __shared__ alignas(16) char lP[16384];
    const int tid = threadIdx.x;
    const int w = tid >> 6, l = tid & 63, g = l >> 4, li = l & 15;
    const int bh = blockIdx.y, b = bh >> 4, h = bh & 15;
    const int q0 = blockIdx.x * 128 + w * 32;
    char* pb = lP + w * 4096;

    const short8* Q8 = (const short8*)Qf;
    const short8* Kt8 = (const short8*)Kf + (size_t)bh * 16384;   // + t*512 + f*64 + l
    const short8* Vt8 = (const short8*)Vf + (size_t)bh * 16384;
    float* attnb = attn + (size_t)bh * S * S;

    // Q fragments (B-operand): lane holds Q[q=qt*16+li][k=kf*32+g*8+j]
    short8 qfr[2][2];
#pragma unroll
    for (int qi = 0; qi < 2; ++qi)
#pragma unroll
        for (int kf = 0; kf < 2; ++kf)
            qfr[qi][kf] = Q8[(((size_t)bh * 128 + (q0 >> 4) + qi) * 2 + kf) * 64 + l];

    short8 ka[8], kb_[8];

    // ---- pass 1: denominators ----
    float run_l[2] = {0.f, 0.f};
    ldfr(ka, Kt8, l);
    for (int t = 0; t < 32; t += 2) {
        ldfr(kb_, Kt8 + (t + 1) * 512, l);
        {
            f32x4 sc[4][2] = {};
            qk_mfma(ka, qfr, sc);
            expsum(sc, run_l);
        }
        if (t + 2 < 32) ldfr(ka, Kt8 + (t + 2) * 512, l);
        {
            f32x4 sc[4][2] = {};
            qk_mfma(kb_, qfr, sc);
            expsum(sc, run_l);
        }
    }
    const float invl[2] = {1.f / run_l[0], 1.f / run_l[1]};

    // ---- pass 2: probs + PV ----
    f32x4 oacc[4][2] = {};   // [dfrag][qfrag], D[d][q]
    short8 vv[8];
    ldfr(ka, Kt8, l);
    for (int t = 0; t < 32; t += 2) {
        ldfr(vv, Vt8 + t * 512, l);          // V(t) in flight under QK^T(t)
        ldfr(kb_, Kt8 + (t + 1) * 512, l);   // K(t+1) in flight
        p2tile(t, ka, vv, qfr, invl, attnb, pb, oacc, q0, g, li);
        ldfr(vv, Vt8 + (t + 1) * 512, l);    // V(t+1) in flight under QK^T(t+1)
        if (t + 2 < 32) ldfr(ka, Kt8 + (t + 2) * 512, l);
        p2tile(t + 1, kb_, vv, qfr, invl, attnb, pb, oacc, q0, g, li);
    }

    // vtb [B*S][H*HD] bf16
#pragma unroll
    for (int df = 0; df < 4; ++df)
#pragma unroll
        for (int qi = 0; qi < 2; ++qi) {
            const int qrow = q0 + qi * 16 + li;
            const size_t m = (size_t)b * S + qrow;
            const int d0 = df * 16 + g * 4;
            uint2 o = {pkbf(oacc[df][qi][0], oacc[df][qi][1]),
                       pkbf(oacc[df][qi][2], oacc[df][qi][3])};
            *(uint2*)(vtb + m * D + h * HD + d0) = o;
        }
}

// ---------------------------------------------------------------------------
extern "C" void kernel_launch(void* const* d_in, const int* in_sizes, int n_in,
                              void* d_out, int out_size, void* d_ws, size_t ws_size,
                              hipStream_t stream) {
    const float* x     = (const float*)d_in[0];
    const float* W_qkv = (const float*)d_in[1];
    const float* b_qkv = (const float*)d_in[2];
    const float* W_out = (const float*)d_in[3];
    const float* b_out = (const float*)d_in[4];

    float* out  = (float*)d_out;                    // [B,S,D] f32
    float* attn = out + (size_t)BS * S * D;         // [B,H,S,S] f32

    char* ws = (char*)d_ws;
    unsigned short* xb  = (unsigned short*)(ws);                    // [4096][1024]
    unsigned short* wqT = (unsigned short*)(ws + 8388608);          // [3072][1024]
    unsigned short* woT = (unsigned short*)(ws + 14680064);         // [1024][1024]
    unsigned short* Qf  = (unsigned short*)(ws + 16777216);         // frag layout
    unsigned short* Kf  = (unsigned short*)(ws + 25165824);         // frag layout
    unsigned short* Vf  = (unsigned short*)(ws + 33554432);         // frag layout
    unsigned short* vtb = (unsigned short*)(ws + 41943040);         // [4096][1024]

    k_cvt<<<4096, 256, 0, stream>>>(x, xb, (BS * S * D) / 4);
    k_tr<<<dim3(48, 16), 256, 0, stream>>>(W_qkv, wqT, D, 3 * D);
    k_tr<<<dim3(16, 16), 256, 0, stream>>>(W_out, woT, D, D);

    k_qkv<<<dim3(32, 24), 256, 0, stream>>>(wqT, xb, b_qkv, Qf, Kf, Vf);
    k_attn<<<dim3(16, 32), 256, 0, stream>>>(Qf, Kf, Vf, attn, vtb);
    k_out<<<dim3(32, 8), 256, 0, stream>>>(woT, vtb, b_out, out);
}

// Round 6
// 313.945 us; speedup vs baseline: 4.0503x; 1.0357x over previous
//
#include <hip/hip_runtime.h>
#include <hip/hip_bf16.h>
#include <cstddef>
#include <cstdint>

typedef __attribute__((ext_vector_type(8))) short short8;   // 8 bf16 (4 VGPR)
typedef __attribute__((ext_vector_type(4))) float f32x4;    // MFMA C/D frag
typedef __attribute__((ext_vector_type(4))) unsigned short us4;

constexpr int BS = 2;     // batch
constexpr int S  = 2048;
constexpr int D  = 1024;
constexpr int H  = 16;
constexpr int HD = 64;
constexpr int BH = BS * H;                  // 32
constexpr float QSCALE = 0.18033688011112042f;  // 0.125 * log2(e)

// f32 -> bf16 round-to-nearest-even (scalar)
__device__ __forceinline__ unsigned short f2bf(float x) {
    unsigned u = __builtin_bit_cast(unsigned, x);
    u += 0x7fffu + ((u >> 16) & 1u);
    return (unsigned short)(u >> 16);
}

// packed f32 pair -> 2 bf16 in one u32 (lo = a, hi = b)
__device__ __forceinline__ unsigned pkbf(float a, float b) {
    unsigned r;
    asm("v_cvt_pk_bf16_f32 %0, %1, %2" : "=v"(r) : "v"(a), "v"(b));
    return r;
}

// native 2^x
__device__ __forceinline__ float fexp2(float x) {
    float r; asm("v_exp_f32 %0, %1" : "=v"(r) : "v"(x)); return r;
}

__device__ __forceinline__ f32x4 MFMA(short8 a, short8 b, f32x4 c) {
    return __builtin_amdgcn_mfma_f32_16x16x32_bf16(a, b, c, 0, 0, 0);
}

// ---------------------------------------------------------------------------
// Async staging (m97-style): 16384-B tile = 128 rows x 128 B, LINEAR LDS.
// Global src per-lane, LDS dest wave-uniform base (+ lane*16 by HW).
// ---------------------------------------------------------------------------
__device__ __forceinline__ void stage_async(char* lds, const char* g,
                                            int gstride, int tid) {
    const int w = tid >> 6, l = tid & 63;
#pragma unroll
    for (int i = 0; i < 4; ++i) {
        const int fb = i * 4096 + w * 1024;          // wave-uniform
        const int f  = fb + l * 16;
        const int row = f >> 7, colb = f & 127;
        __builtin_amdgcn_global_load_lds(
            (const __attribute__((address_space(1))) uint32_t*)(g + (size_t)row * gstride + colb),
            (__attribute__((address_space(3))) uint32_t*)(lds + fb),
            16, 0, 0);
    }
}

// linear fragment load
__device__ __forceinline__ short8 fldl(const char* lds, int row, int kb) {
    return *(const short8*)(lds + row * 128 + kb);
}

// swizzled fragment load (attention P tile only)
__device__ __forceinline__ short8 fld(const char* lds, int row, int kb) {
    return *(const short8*)(lds + row * 128 + (kb ^ ((row & 7) << 4)));
}

// ---------------------------------------------------------------------------
// Convert x (f32) -> bf16
// ---------------------------------------------------------------------------
__global__ __launch_bounds__(256) void k_cvt(const float* __restrict__ src,
                                             unsigned short* __restrict__ dst,
                                             int n4) {
    int i = blockIdx.x * 256 + threadIdx.x;
    if (i < n4) {
        f32x4 v = ((const f32x4*)src)[i];
        us4 o = {f2bf(v[0]), f2bf(v[1]), f2bf(v[2]), f2bf(v[3])};
        ((us4*)dst)[i] = o;
    }
}

// ---------------------------------------------------------------------------
// Transpose f32 [K][N] -> bf16 [N][K]
// ---------------------------------------------------------------------------
__global__ __launch_bounds__(256) void k_tr(const float* __restrict__ src,
                                            unsigned short* __restrict__ dst,
                                            int K, int N) {
    __shared__ float t[64][65];
    const int k0 = blockIdx.y * 64, n0 = blockIdx.x * 64;
    const int rr = threadIdx.x >> 4, c4 = (threadIdx.x & 15) * 4;
#pragma unroll
    for (int u = 0; u < 4; ++u) {
        int r = rr + u * 16;
        f32x4 v = *(const f32x4*)(src + (size_t)(k0 + r) * N + n0 + c4);
        t[r][c4 + 0] = v[0]; t[r][c4 + 1] = v[1];
        t[r][c4 + 2] = v[2]; t[r][c4 + 3] = v[3];
    }
    __syncthreads();
#pragma unroll
    for (int u = 0; u < 4; ++u) {
        int r = rr + u * 16;
        us4 o = {f2bf(t[c4 + 0][r]), f2bf(t[c4 + 1][r]),
                 f2bf(t[c4 + 2][r]), f2bf(t[c4 + 3][r])};
        *(us4*)(dst + (size_t)(n0 + r) * K + k0 + c4) = o;
    }
}

// ---------------------------------------------------------------------------
// GEMM core (m97 structure): 128(n) x 128(m) tile, BK=64, 4 waves (2n x 2m),
// global_load_lds staging, linear LDS, two barriers per K-step.
// acc[i][j][r] = C[token m = mBase + j*16 + li][feature n = nBase + i*16 + g*4 + r]
// ---------------------------------------------------------------------------
__device__ __forceinline__ void gemm_core(const char* Ag, const char* Bg,
                                          char* lA, char* lB, int tid,
                                          f32x4 (&acc)[4][4]) {
    const int l = tid & 63, g = l >> 4, li = l & 15;
    const int w = tid >> 6, wn = w >> 1, wm = w & 1;
    for (int k0 = 0; k0 < 1024; k0 += 64) {
        __syncthreads();
        stage_async(lA, Ag + k0 * 2, 2048, tid);
        stage_async(lB, Bg + k0 * 2, 2048, tid);
        __syncthreads();   // compiler drains vmcnt(0) before barrier
#pragma unroll
        for (int kf = 0; kf < 2; ++kf) {
            short8 a[4], b[4];
#pragma unroll
            for (int i = 0; i < 4; ++i) a[i] = fldl(lA, wn * 64 + i * 16 + li, kf * 64 + g * 16);
#pragma unroll
            for (int i = 0; i < 4; ++i) b[i] = fldl(lB, wm * 64 + i * 16 + li, kf * 64 + g * 16);
#pragma unroll
            for (int i = 0; i < 4; ++i)
#pragma unroll
                for (int j = 0; j < 4; ++j) acc[i][j] = MFMA(a[i], b[j], acc[i][j]);
        }
    }
}

// ---------------------------------------------------------------------------
// QKV projection: A = WqT [3072][1024], B = xb [4096][1024].
// Epilogue scatters into MFMA-fragment layouts:
//   Qf: [bh][qt=s/16][kf=d/32][lane=g*16+(s%16)][j=d%8]   (QSCALE folded)
//   Kf: [bh][t=s/64][kf=d/32][i=(s/16)%4][lane=g*16+(s%16)][j=d%8]
//   Vf: [bh][t][kvf=(s/32)%2][df=d/16][lane=gv*16+(d%16)][j=s%8]
// ---------------------------------------------------------------------------
__global__ __launch_bounds__(256) void k_qkv(const unsigned short* __restrict__ WqT,
                                             const unsigned short* __restrict__ xb,
                                             const float* __restrict__ bias,
                                             unsigned short* __restrict__ Qf,
                                             unsigned short* __restrict__ Kf,
                                             unsigned short* __restrict__ Vf) {
    __shared__ alignas(16) char lA[16384];
    __shared__ alignas(16) char lB[16384];
    const int tid = threadIdx.x;
    f32x4 acc[4][4] = {};
    const char* Ag = (const char*)(WqT + (size_t)blockIdx.y * 128 * 1024);
    const char* Bg = (const char*)(xb  + (size_t)blockIdx.x * 128 * 1024);
    gemm_core(Ag, Bg, lA, lB, tid, acc);

    const int l = tid & 63, g = l >> 4, li = l & 15;
    const int w = tid >> 6, wn = w >> 1, wm = w & 1;
    const int nBase = blockIdx.y * 128 + wn * 64;
    const int mBase = blockIdx.x * 128 + wm * 64;
#pragma unroll
    for (int i = 0; i < 4; ++i)
#pragma unroll
        for (int j = 0; j < 4; ++j) {
            const int n0 = nBase + i * 16 + g * 4;
            const int m  = mBase + j * 16 + li;
            const int bb = m >> 11, s = m & (S - 1);
            const int h = n0 / 192, r2 = n0 % 192, tt = r2 >> 6, d0 = r2 & 63;
            const int bh_ = bb * H + h;
            f32x4 v = acc[i][j];
            const f32x4 b4 = *(const f32x4*)(bias + n0);
            v += b4;
            if (tt == 0) {
                v[0] *= QSCALE; v[1] *= QSCALE; v[2] *= QSCALE; v[3] *= QSCALE;
                us4 o = {f2bf(v[0]), f2bf(v[1]), f2bf(v[2]), f2bf(v[3])};
                size_t e = (((size_t)bh_ * 128 + (s >> 4)) * 2 + (d0 >> 5)) * 512
                         + (((d0 & 31) >> 3) * 16 + (s & 15)) * 8 + (d0 & 7);
                *(us4*)(Qf + e) = o;
            } else if (tt == 1) {
                us4 o = {f2bf(v[0]), f2bf(v[1]), f2bf(v[2]), f2bf(v[3])};
                size_t e = ((((size_t)bh_ * 32 + (s >> 6)) * 2 + (d0 >> 5)) * 4
                            + ((s >> 4) & 3)) * 512
                         + (((d0 & 31) >> 3) * 16 + (s & 15)) * 8 + (d0 & 7);
                *(us4*)(Kf + e) = o;
            } else {
                size_t vbase = ((((size_t)bh_ * 32 + (s >> 6)) * 2 + ((s >> 5) & 1)) * 4
                                + (d0 >> 4)) * 512
                             + ((s >> 3) & 3) * 128 + (s & 7);
#pragma unroll
                for (int r = 0; r < 4; ++r)
                    Vf[vbase + ((d0 & 15) + r) * 8] = f2bf(v[r]);
            }
        }
}

// ---------------------------------------------------------------------------
// Output projection: A = WoT [1024][1024], B = vtb [4096][1024], f32 out + bias
// grid MUST be dim3(32, 8): blockIdx.x -> m tiles (4096/128), blockIdx.y -> n
// tiles (1024/128).  (Round-5 failure was this grid swapped.)
// ---------------------------------------------------------------------------
__global__ __launch_bounds__(256) void k_out(const unsigned short* __restrict__ WoT,
                                             const unsigned short* __restrict__ vtb,
                                             const float* __restrict__ bias,
                                             float* __restrict__ outp) {
    __shared__ alignas(16) char lA[16384];
    __shared__ alignas(16) char lB[16384];
    const int tid = threadIdx.x;
    f32x4 acc[4][4] = {};
    const char* Ag = (const char*)(WoT + (size_t)blockIdx.y * 128 * 1024);
    const char* Bg = (const char*)(vtb + (size_t)blockIdx.x * 128 * 1024);
    gemm_core(Ag, Bg, lA, lB, tid, acc);

    const int l = tid & 63, g = l >> 4, li = l & 15;
    const int w = tid >> 6, wn = w >> 1, wm = w & 1;
    const int nBase = blockIdx.y * 128 + wn * 64;
    const int mBase = blockIdx.x * 128 + wm * 64;
#pragma unroll
    for (int i = 0; i < 4; ++i)
#pragma unroll
        for (int j = 0; j < 4; ++j) {
            const int n0 = nBase + i * 16 + g * 4;
            const int m  = mBase + j * 16 + li;
            f32x4 v = acc[i][j];
            const f32x4 b4 = *(const f32x4*)(bias + n0);
            v += b4;
            *(f32x4*)(outp + (size_t)m * D + n0) = v;
        }
}

// ---------------------------------------------------------------------------
// Attention helpers
// ---------------------------------------------------------------------------
__device__ __forceinline__ void ldfr(short8 (&b)[8], const short8* base, int l) {
#pragma unroll
    for (int f = 0; f < 8; ++f) b[f] = base[f * 64 + l];
}

__device__ __forceinline__ void qk_mfma(const short8 (&kb)[8],
                                        const short8 (&qfr)[2][2],
                                        f32x4 (&sc)[4][2]) {
    __builtin_amdgcn_s_setprio(1);
#pragma unroll
    for (int kf = 0; kf < 2; ++kf)
#pragma unroll
        for (int i = 0; i < 4; ++i)
#pragma unroll
            for (int qi = 0; qi < 2; ++qi)
                sc[i][qi] = MFMA(kb[kf * 4 + i], qfr[qi][kf], sc[i][qi]);
    __builtin_amdgcn_s_setprio(0);
}

// ---------------------------------------------------------------------------
// k_den: softmax denominators. 16 q-rows/wave, grid (32, BH) = 1024 blocks.
// ---------------------------------------------------------------------------
__global__ __launch_bounds__(256) void k_den(const unsigned short* __restrict__ Qf,
                                             const unsigned short* __restrict__ Kf,
                                             float* __restrict__ invl_buf) {
    const int tid = threadIdx.x;
    const int w = tid >> 6, l = tid & 63, li = l & 15;
    const int bh = blockIdx.y;
    const int q0 = blockIdx.x * 64 + w * 16;

    const short8* Q8 = (const short8*)Qf;
    const short8* Kt8 = (const short8*)Kf + (size_t)bh * 16384;

    short8 qfr[2];   // kf = 0,1
#pragma unroll
    for (int kf = 0; kf < 2; ++kf)
        qfr[kf] = Q8[(((size_t)bh * 128 + (q0 >> 4)) * 2 + kf) * 64 + l];

    short8 ka[8], kb_[8];
    float run = 0.f;
    ldfr(ka, Kt8, l);
    for (int t = 0; t < 32; t += 2) {
        ldfr(kb_, Kt8 + (t + 1) * 512, l);
        {
            f32x4 sc[4] = {};
            __builtin_amdgcn_s_setprio(1);
#pragma unroll
            for (int kf = 0; kf < 2; ++kf)
#pragma unroll
                for (int i = 0; i < 4; ++i)
                    sc[i] = MFMA(ka[kf * 4 + i], qfr[kf], sc[i]);
            __builtin_amdgcn_s_setprio(0);
            float part = 0.f;
#pragma unroll
            for (int i = 0; i < 4; ++i)
#pragma unroll
                for (int r = 0; r < 4; ++r) part += fexp2(sc[i][r]);
            run += part;
        }
        if (t + 2 < 32) ldfr(ka, Kt8 + (t + 2) * 512, l);
        {
            f32x4 sc[4] = {};
            __builtin_amdgcn_s_setprio(1);
#pragma unroll
            for (int kf = 0; kf < 2; ++kf)
#pragma unroll
                for (int i = 0; i < 4; ++i)
                    sc[i] = MFMA(kb_[kf * 4 + i], qfr[kf], sc[i]);
            __builtin_amdgcn_s_setprio(0);
            float part = 0.f;
#pragma unroll
            for (int i = 0; i < 4; ++i)
#pragma unroll
                for (int r = 0; r < 4; ++r) part += fexp2(sc[i][r]);
            run += part;
        }
    }
    run += __shfl_xor(run, 16);
    run += __shfl_xor(run, 32);
    if (l < 16)
        invl_buf[(size_t)bh * S + q0 + li] = 1.0f / run;
}

// ---------------------------------------------------------------------------
// k_attn2: probs + PV (pass 2 only). 32 q-rows/wave, grid (16, BH).
// K register-double-buffered, V issued early; invl preloaded from k_den.
// ---------------------------------------------------------------------------
__device__ __forceinline__ void p2tile(int t, const short8 (&kb)[8],
                                       const short8 (&vb)[8],
                                       const short8 (&qfr)[2][2],
                                       const float (&invl)[2],
                                       float* __restrict__ attnb, char* pb,
                                       f32x4 (&oacc)[4][2],
                                       int q0, int g, int li) {
    f32x4 sc[4][2] = {};
    qk_mfma(kb, qfr, sc);
#pragma unroll
    for (int i = 0; i < 4; ++i)
#pragma unroll
        for (int qi = 0; qi < 2; ++qi) {
            f32x4 p;
#pragma unroll
            for (int r = 0; r < 4; ++r) p[r] = fexp2(sc[i][qi][r]) * invl[qi];
            const int qrow = q0 + qi * 16 + li;
            *(f32x4*)(attnb + (size_t)qrow * S + t * 64 + i * 16 + g * 4) = p;
            const int row = qi * 16 + li;
            uint2 o = {pkbf(p[0], p[1]), pkbf(p[2], p[3])};
            *(uint2*)(pb + row * 128 + ((i * 32 + g * 8) ^ ((row & 7) << 4))) = o;
        }
    short8 pa[2][2];
#pragma unroll
    for (int kvf = 0; kvf < 2; ++kvf)
#pragma unroll
        for (int qi = 0; qi < 2; ++qi)
            pa[kvf][qi] = fld(pb, qi * 16 + li, kvf * 64 + g * 16);
    __builtin_amdgcn_s_setprio(1);
#pragma unroll
    for (int kvf = 0; kvf < 2; ++kvf)
#pragma unroll
        for (int df = 0; df < 4; ++df)
#pragma unroll
            for (int qi = 0; qi < 2; ++qi)
                oacc[df][qi] = MFMA(vb[kvf * 4 + df], pa[kvf][qi], oacc[df][qi]);
    __builtin_amdgcn_s_setprio(0);
}

__global__ __launch_bounds__(256, 2) void k_attn2(const unsigned short* __restrict__ Qf,
                                                  const unsigned short* __restrict__ Kf,
                                                  const unsigned short* __restrict__ Vf,
                                                  const float* __restrict__ invl_buf,
                                                  float* __restrict__ attn,
                                                  unsigned short* __restrict__ vtb) {
    __shared__ alignas(16) char lP[16384];
    const int tid = threadIdx.x;
    const int w = tid >> 6, l = tid & 63, g = l >> 4, li = l & 15;
    const int bh = blockIdx.y, b = bh >> 4, h = bh & 15;
    const int q0 = blockIdx.x * 128 + w * 32;
    char* pb = lP + w * 4096;

    const short8* Q8 = (const short8*)Qf;
    const short8* Kt8 = (const short8*)Kf + (size_t)bh * 16384;
    const short8* Vt8 = (const short8*)Vf + (size_t)bh * 16384;
    float* attnb = attn + (size_t)bh * S * S;

    short8 qfr[2][2];
#pragma unroll
    for (int qi = 0; qi < 2; ++qi)
#pragma unroll
        for (int kf = 0; kf < 2; ++kf)
            qfr[qi][kf] = Q8[(((size_t)bh * 128 + (q0 >> 4) + qi) * 2 + kf) * 64 + l];

    const float invl[2] = {invl_buf[(size_t)bh * S + q0 + li],
                           invl_buf[(size_t)bh * S + q0 + 16 + li]};

    f32x4 oacc[4][2] = {};   // [dfrag][qfrag], D[d][q]
    short8 ka[8], kb_[8], vv[8];
    ldfr(ka, Kt8, l);
    for (int t = 0; t < 32; t += 2) {
        ldfr(vv, Vt8 + t * 512, l);          // V(t) in flight under QK^T(t)
        ldfr(kb_, Kt8 + (t + 1) * 512, l);   // K(t+1) in flight
        p2tile(t, ka, vv, qfr, invl, attnb, pb, oacc, q0, g, li);
        ldfr(vv, Vt8 + (t + 1) * 512, l);    // V(t+1) in flight
        if (t + 2 < 32) ldfr(ka, Kt8 + (t + 2) * 512, l);
        p2tile(t + 1, kb_, vv, qfr, invl, attnb, pb, oacc, q0, g, li);
    }

    // vtb [B*S][H*HD] bf16
#pragma unroll
    for (int df = 0; df < 4; ++df)
#pragma unroll
        for (int qi = 0; qi < 2; ++qi) {
            const int qrow = q0 + qi * 16 + li;
            const size_t m = (size_t)b * S + qrow;
            const int d0 = df * 16 + g * 4;
            uint2 o = {pkbf(oacc[df][qi][0], oacc[df][qi][1]),
                       pkbf(oacc[df][qi][2], oacc[df][qi][3])};
            *(uint2*)(vtb + m * D + h * HD + d0) = o;
        }
}

// ---------------------------------------------------------------------------
extern "C" void kernel_launch(void* const* d_in, const int* in_sizes, int n_in,
                              void* d_out, int out_size, void* d_ws, size_t ws_size,
                              hipStream_t stream) {
    const float* x     = (const float*)d_in[0];
    const float* W_qkv = (const float*)d_in[1];
    const float* b_qkv = (const float*)d_in[2];
    const float* W_out = (const float*)d_in[3];
    const float* b_out = (const float*)d_in[4];

    float* out  = (float*)d_out;                    // [B,S,D] f32
    float* attn = out + (size_t)BS * S * D;         // [B,H,S,S] f32

    char* ws = (char*)d_ws;
    unsigned short* xb   = (unsigned short*)(ws);                    // [4096][1024]
    unsigned short* wqT  = (unsigned short*)(ws + 8388608);          // [3072][1024]
    unsigned short* woT  = (unsigned short*)(ws + 14680064);         // [1024][1024]
    unsigned short* Qf   = (unsigned short*)(ws + 16777216);         // frag layout
    unsigned short* Kf   = (unsigned short*)(ws + 25165824);         // frag layout
    unsigned short* Vf   = (unsigned short*)(ws + 33554432);         // frag layout
    unsigned short* vtb  = (unsigned short*)(ws + 41943040);         // [4096][1024]
    float*          invl = (float*)(ws + 50331648);                  // [BH*S]

    k_cvt<<<4096, 256, 0, stream>>>(x, xb, (BS * S * D) / 4);
    k_tr<<<dim3(48, 16), 256, 0, stream>>>(W_qkv, wqT, D, 3 * D);
    k_tr<<<dim3(16, 16), 256, 0, stream>>>(W_out, woT, D, D);

    k_qkv<<<dim3(32, 24), 256, 0, stream>>>(wqT, xb, b_qkv, Qf, Kf, Vf);
    k_den<<<dim3(32, BH), 256, 0, stream>>>(Qf, Kf, invl);
    k_attn2<<<dim3(16, BH), 256, 0, stream>>>(Qf, Kf, Vf, invl, attn, vtb);
    k_out<<<dim3(32, 8), 256, 0, stream>>>(woT, vtb, b_out, out);   // x=m(32), y=n(8)
}

// Round 7
// 265.018 us; speedup vs baseline: 4.7981x; 1.1846x over previous
//
#include <hip/hip_runtime.h>
#include <hip/hip_bf16.h>
#include <cstddef>
#include <cstdint>

typedef __attribute__((ext_vector_type(8))) short short8;   // 8 bf16 (4 VGPR)
typedef __attribute__((ext_vector_type(4))) float f32x4;    // MFMA C/D frag
typedef __attribute__((ext_vector_type(4))) unsigned short us4;

constexpr int BS = 2;     // batch
constexpr int S  = 2048;
constexpr int D  = 1024;
constexpr int H  = 16;
constexpr int HD = 64;
constexpr int BH = BS * H;                  // 32
constexpr float QSCALE = 0.18033688011112042f;  // 0.125 * log2(e)

// f32 -> bf16 round-to-nearest-even (scalar)
__device__ __forceinline__ unsigned short f2bf(float x) {
    unsigned u = __builtin_bit_cast(unsigned, x);
    u += 0x7fffu + ((u >> 16) & 1u);
    return (unsigned short)(u >> 16);
}

// packed f32 pair -> 2 bf16 in one u32 (lo = a, hi = b)
__device__ __forceinline__ unsigned pkbf(float a, float b) {
    unsigned r;
    asm("v_cvt_pk_bf16_f32 %0, %1, %2" : "=v"(r) : "v"(a), "v"(b));
    return r;
}

// native 2^x
__device__ __forceinline__ float fexp2(float x) {
    float r; asm("v_exp_f32 %0, %1" : "=v"(r) : "v"(x)); return r;
}

__device__ __forceinline__ f32x4 MFMA(short8 a, short8 b, f32x4 c) {
    return __builtin_amdgcn_mfma_f32_16x16x32_bf16(a, b, c, 0, 0, 0);
}

// ---------------------------------------------------------------------------
// Async staging (m97-style): 16384-B tile = 128 rows x 128 B, LINEAR LDS.
// ---------------------------------------------------------------------------
__device__ __forceinline__ void stage_async(char* lds, const char* g,
                                            int gstride, int tid) {
    const int w = tid >> 6, l = tid & 63;
#pragma unroll
    for (int i = 0; i < 4; ++i) {
        const int fb = i * 4096 + w * 1024;          // wave-uniform
        const int f  = fb + l * 16;
        const int row = f >> 7, colb = f & 127;
        __builtin_amdgcn_global_load_lds(
            (const __attribute__((address_space(1))) uint32_t*)(g + (size_t)row * gstride + colb),
            (__attribute__((address_space(3))) uint32_t*)(lds + fb),
            16, 0, 0);
    }
}

// linear fragment load
__device__ __forceinline__ short8 fldl(const char* lds, int row, int kb) {
    return *(const short8*)(lds + row * 128 + kb);
}

// swizzled fragment load (attention P tile only)
__device__ __forceinline__ short8 fld(const char* lds, int row, int kb) {
    return *(const short8*)(lds + row * 128 + (kb ^ ((row & 7) << 4)));
}

// ---------------------------------------------------------------------------
// Convert x (f32) -> bf16
// ---------------------------------------------------------------------------
__global__ __launch_bounds__(256) void k_cvt(const float* __restrict__ src,
                                             unsigned short* __restrict__ dst,
                                             int n4) {
    int i = blockIdx.x * 256 + threadIdx.x;
    if (i < n4) {
        f32x4 v = ((const f32x4*)src)[i];
        us4 o = {f2bf(v[0]), f2bf(v[1]), f2bf(v[2]), f2bf(v[3])};
        ((us4*)dst)[i] = o;
    }
}

// ---------------------------------------------------------------------------
// Transpose f32 [K][N] -> bf16 [N][K]
// ---------------------------------------------------------------------------
__global__ __launch_bounds__(256) void k_tr(const float* __restrict__ src,
                                            unsigned short* __restrict__ dst,
                                            int K, int N) {
    __shared__ float t[64][65];
    const int k0 = blockIdx.y * 64, n0 = blockIdx.x * 64;
    const int rr = threadIdx.x >> 4, c4 = (threadIdx.x & 15) * 4;
#pragma unroll
    for (int u = 0; u < 4; ++u) {
        int r = rr + u * 16;
        f32x4 v = *(const f32x4*)(src + (size_t)(k0 + r) * N + n0 + c4);
        t[r][c4 + 0] = v[0]; t[r][c4 + 1] = v[1];
        t[r][c4 + 2] = v[2]; t[r][c4 + 3] = v[3];
    }
    __syncthreads();
#pragma unroll
    for (int u = 0; u < 4; ++u) {
        int r = rr + u * 16;
        us4 o = {f2bf(t[c4 + 0][r]), f2bf(t[c4 + 1][r]),
                 f2bf(t[c4 + 2][r]), f2bf(t[c4 + 3][r])};
        *(us4*)(dst + (size_t)(n0 + r) * K + k0 + c4) = o;
    }
}

// ---------------------------------------------------------------------------
// GEMM core (m97 structure): 128(n) x 128(m) tile, BK=64, 4 waves (2n x 2m).
// ---------------------------------------------------------------------------
__device__ __forceinline__ void gemm_core(const char* Ag, const char* Bg,
                                          char* lA, char* lB, int tid,
                                          f32x4 (&acc)[4][4]) {
    const int l = tid & 63, g = l >> 4, li = l & 15;
    const int w = tid >> 6, wn = w >> 1, wm = w & 1;
    for (int k0 = 0; k0 < 1024; k0 += 64) {
        __syncthreads();
        stage_async(lA, Ag + k0 * 2, 2048, tid);
        stage_async(lB, Bg + k0 * 2, 2048, tid);
        __syncthreads();   // compiler drains vmcnt(0) before barrier
#pragma unroll
        for (int kf = 0; kf < 2; ++kf) {
            short8 a[4], b[4];
#pragma unroll
            for (int i = 0; i < 4; ++i) a[i] = fldl(lA, wn * 64 + i * 16 + li, kf * 64 + g * 16);
#pragma unroll
            for (int i = 0; i < 4; ++i) b[i] = fldl(lB, wm * 64 + i * 16 + li, kf * 64 + g * 16);
#pragma unroll
            for (int i = 0; i < 4; ++i)
#pragma unroll
                for (int j = 0; j < 4; ++j) acc[i][j] = MFMA(a[i], b[j], acc[i][j]);
        }
    }
}

// ---------------------------------------------------------------------------
// QKV projection: A = WqT [3072][1024], B = xb [4096][1024].
// Epilogue scatters into MFMA-fragment layouts:
//   Qf: [bh][qt=s/16][kf=d/32][lane=g*16+(s%16)][j=d%8]   (QSCALE folded)
//   Kf: [bh][t=s/64][kf=d/32][i=(s/16)%4][lane=g*16+(s%16)][j=d%8]
//   Vf: [bh][t][kvf=(s/32)%2][df=d/16][lane=gv*16+(d%16)][j=s%8]
// ---------------------------------------------------------------------------
__global__ __launch_bounds__(256) void k_qkv(const unsigned short* __restrict__ WqT,
                                             const unsigned short* __restrict__ xb,
                                             const float* __restrict__ bias,
                                             unsigned short* __restrict__ Qf,
                                             unsigned short* __restrict__ Kf,
                                             unsigned short* __restrict__ Vf) {
    __shared__ alignas(16) char lA[16384];
    __shared__ alignas(16) char lB[16384];
    const int tid = threadIdx.x;
    f32x4 acc[4][4] = {};
    const char* Ag = (const char*)(WqT + (size_t)blockIdx.y * 128 * 1024);
    const char* Bg = (const char*)(xb  + (size_t)blockIdx.x * 128 * 1024);
    gemm_core(Ag, Bg, lA, lB, tid, acc);

    const int l = tid & 63, g = l >> 4, li = l & 15;
    const int w = tid >> 6, wn = w >> 1, wm = w & 1;
    const int nBase = blockIdx.y * 128 + wn * 64;
    const int mBase = blockIdx.x * 128 + wm * 64;
#pragma unroll
    for (int i = 0; i < 4; ++i)
#pragma unroll
        for (int j = 0; j < 4; ++j) {
            const int n0 = nBase + i * 16 + g * 4;
            const int m  = mBase + j * 16 + li;
            const int bb = m >> 11, s = m & (S - 1);
            const int h = n0 / 192, r2 = n0 % 192, tt = r2 >> 6, d0 = r2 & 63;
            const int bh_ = bb * H + h;
            f32x4 v = acc[i][j];
            const f32x4 b4 = *(const f32x4*)(bias + n0);
            v += b4;
            if (tt == 0) {
                v[0] *= QSCALE; v[1] *= QSCALE; v[2] *= QSCALE; v[3] *= QSCALE;
                us4 o = {f2bf(v[0]), f2bf(v[1]), f2bf(v[2]), f2bf(v[3])};
                size_t e = (((size_t)bh_ * 128 + (s >> 4)) * 2 + (d0 >> 5)) * 512
                         + (((d0 & 31) >> 3) * 16 + (s & 15)) * 8 + (d0 & 7);
                *(us4*)(Qf + e) = o;
            } else if (tt == 1) {
                us4 o = {f2bf(v[0]), f2bf(v[1]), f2bf(v[2]), f2bf(v[3])};
                size_t e = ((((size_t)bh_ * 32 + (s >> 6)) * 2 + (d0 >> 5)) * 4
                            + ((s >> 4) & 3)) * 512
                         + (((d0 & 31) >> 3) * 16 + (s & 15)) * 8 + (d0 & 7);
                *(us4*)(Kf + e) = o;
            } else {
                size_t vbase = ((((size_t)bh_ * 32 + (s >> 6)) * 2 + ((s >> 5) & 1)) * 4
                                + (d0 >> 4)) * 512
                             + ((s >> 3) & 3) * 128 + (s & 7);
#pragma unroll
                for (int r = 0; r < 4; ++r)
                    Vf[vbase + ((d0 & 15) + r) * 8] = f2bf(v[r]);
            }
        }
}

// ---------------------------------------------------------------------------
// Output projection: A = WoT [1024][1024], B = vtb [4096][1024], f32 out + bias
// grid MUST be dim3(32, 8): x -> m tiles, y -> n tiles.
// ---------------------------------------------------------------------------
__global__ __launch_bounds__(256) void k_out(const unsigned short* __restrict__ WoT,
                                             const unsigned short* __restrict__ vtb,
                                             const float* __restrict__ bias,
                                             float* __restrict__ outp) {
    __shared__ alignas(16) char lA[16384];
    __shared__ alignas(16) char lB[16384];
    const int tid = threadIdx.x;
    f32x4 acc[4][4] = {};
    const char* Ag = (const char*)(WoT + (size_t)blockIdx.y * 128 * 1024);
    const char* Bg = (const char*)(vtb + (size_t)blockIdx.x * 128 * 1024);
    gemm_core(Ag, Bg, lA, lB, tid, acc);

    const int l = tid & 63, g = l >> 4, li = l & 15;
    const int w = tid >> 6, wn = w >> 1, wm = w & 1;
    const int nBase = blockIdx.y * 128 + wn * 64;
    const int mBase = blockIdx.x * 128 + wm * 64;
#pragma unroll
    for (int i = 0; i < 4; ++i)
#pragma unroll
        for (int j = 0; j < 4; ++j) {
            const int n0 = nBase + i * 16 + g * 4;
            const int m  = mBase + j * 16 + li;
            f32x4 v = acc[i][j];
            const f32x4 b4 = *(const f32x4*)(bias + n0);
            v += b4;
            *(f32x4*)(outp + (size_t)m * D + n0) = v;
        }
}

// ---------------------------------------------------------------------------
// Attention helpers
// ---------------------------------------------------------------------------
__device__ __forceinline__ void ldfr(short8 (&b)[8], const short8* base, int l) {
#pragma unroll
    for (int f = 0; f < 8; ++f) b[f] = base[f * 64 + l];
}

// ---------------------------------------------------------------------------
// k_den: softmax denominators. 16 q-rows/wave, grid 1024 (XCD-swizzled),
// single kv buffer, 4 waves/SIMD target.
// ---------------------------------------------------------------------------
__global__ __launch_bounds__(256, 4) void k_den(const unsigned short* __restrict__ Qf,
                                                const unsigned short* __restrict__ Kf,
                                                float* __restrict__ invl_buf) {
    const int tid = threadIdx.x;
    const int w = tid >> 6, l = tid & 63, li = l & 15;
    const int wid = (blockIdx.x & 7) * 128 + (blockIdx.x >> 3);   // XCD swizzle
    const int bh = wid >> 5, bx = wid & 31;
    const int q0 = bx * 64 + w * 16;

    const short8* Q8 = (const short8*)Qf;
    const short8* Kt8 = (const short8*)Kf + (size_t)bh * 16384;

    short8 qfr[2];   // kf = 0,1
#pragma unroll
    for (int kf = 0; kf < 2; ++kf)
        qfr[kf] = Q8[(((size_t)bh * 128 + (q0 >> 4)) * 2 + kf) * 64 + l];

    short8 kv[8];
    float run = 0.f;
    ldfr(kv, Kt8, l);
    for (int t = 0; t < 32; ++t) {
        f32x4 sc[4] = {};
        __builtin_amdgcn_s_setprio(1);
#pragma unroll
        for (int kf = 0; kf < 2; ++kf)
#pragma unroll
            for (int i = 0; i < 4; ++i)
                sc[i] = MFMA(kv[kf * 4 + i], qfr[kf], sc[i]);
        __builtin_amdgcn_s_setprio(0);
        if (t < 31) ldfr(kv, Kt8 + (t + 1) * 512, l);   // next K under exp phase
        float part = 0.f;
#pragma unroll
        for (int i = 0; i < 4; ++i)
#pragma unroll
            for (int r = 0; r < 4; ++r) part += fexp2(sc[i][r]);
        run += part;
    }
    run += __shfl_xor(run, 16);
    run += __shfl_xor(run, 32);
    if (l < 16)
        invl_buf[(size_t)bh * S + q0 + li] = 1.0f / run;
}

// ---------------------------------------------------------------------------
// k_attn2: probs + PV. 16 q-rows/wave, grid 1024 (XCD-swizzled).
// Single kv[8] register block time-shared between K and V (K dead after
// QK^T MFMAs issue; V dead after PV MFMAs issue). Non-temporal prob writes.
// ---------------------------------------------------------------------------
__global__ __launch_bounds__(256, 4) void k_attn2(const unsigned short* __restrict__ Qf,
                                                  const unsigned short* __restrict__ Kf,
                                                  const unsigned short* __restrict__ Vf,
                                                  const float* __restrict__ invl_buf,
                                                  float* __restrict__ attn,
                                                  unsigned short* __restrict__ vtb) {
    __shared__ alignas(16) char lP[8192];
    const int tid = threadIdx.x;
    const int w = tid >> 6, l = tid & 63, g = l >> 4, li = l & 15;
    const int wid = (blockIdx.x & 7) * 128 + (blockIdx.x >> 3);   // XCD swizzle
    const int bh = wid >> 5, bx = wid & 31;
    const int b = bh >> 4, h = bh & 15;
    const int q0 = bx * 64 + w * 16;
    char* pb = lP + w * 2048;   // per-wave [16 q][64 kv] bf16, swizzled

    const short8* Q8 = (const short8*)Qf;
    const short8* Kt8 = (const short8*)Kf + (size_t)bh * 16384;
    const short8* Vt8 = (const short8*)Vf + (size_t)bh * 16384;
    float* attnb = attn + (size_t)bh * S * S;

    short8 qfr[2];
#pragma unroll
    for (int kf = 0; kf < 2; ++kf)
        qfr[kf] = Q8[(((size_t)bh * 128 + (q0 >> 4)) * 2 + kf) * 64 + l];

    const float invl = invl_buf[(size_t)bh * S + q0 + li];

    f32x4 oacc[4] = {};   // [dfrag], D[d = df*16+g*4+r][q = li]
    short8 kv[8];
    ldfr(kv, Kt8, l);
    for (int t = 0; t < 32; ++t) {
        f32x4 sc[4] = {};
        __builtin_amdgcn_s_setprio(1);
#pragma unroll
        for (int kf = 0; kf < 2; ++kf)
#pragma unroll
            for (int i = 0; i < 4; ++i)
                sc[i] = MFMA(kv[kf * 4 + i], qfr[kf], sc[i]);
        __builtin_amdgcn_s_setprio(0);
        ldfr(kv, Vt8 + t * 512, l);   // V(t) in flight under exp/store phase

#pragma unroll
        for (int i = 0; i < 4; ++i) {
            f32x4 p;
#pragma unroll
            for (int r = 0; r < 4; ++r) p[r] = fexp2(sc[i][r]) * invl;
            __builtin_nontemporal_store(
                p, (f32x4*)(attnb + (size_t)(q0 + li) * S + t * 64 + i * 16 + g * 4));
            uint2 o = {pkbf(p[0], p[1]), pkbf(p[2], p[3])};
            *(uint2*)(pb + li * 128 + ((i * 32 + g * 8) ^ ((li & 7) << 4))) = o;
        }
        short8 pa[2];
#pragma unroll
        for (int kvf = 0; kvf < 2; ++kvf)
            pa[kvf] = fld(pb, li, kvf * 64 + g * 16);
        __builtin_amdgcn_s_setprio(1);
#pragma unroll
        for (int kvf = 0; kvf < 2; ++kvf)
#pragma unroll
            for (int df = 0; df < 4; ++df)
                oacc[df] = MFMA(kv[kvf * 4 + df], pa[kvf], oacc[df]);
        __builtin_amdgcn_s_setprio(0);
        if (t < 31) ldfr(kv, Kt8 + (t + 1) * 512, l);   // K(t+1) in flight
    }

    // vtb [B*S][H*HD] bf16
#pragma unroll
    for (int df = 0; df < 4; ++df) {
        const int qrow = q0 + li;
        const size_t m = (size_t)b * S + qrow;
        const int d0 = df * 16 + g * 4;
        uint2 o = {pkbf(oacc[df][0], oacc[df][1]),
                   pkbf(oacc[df][2], oacc[df][3])};
        *(uint2*)(vtb + m * D + h * HD + d0) = o;
    }
}

// ---------------------------------------------------------------------------
extern "C" void kernel_launch(void* const* d_in, const int* in_sizes, int n_in,
                              void* d_out, int out_size, void* d_ws, size_t ws_size,
                              hipStream_t stream) {
    const float* x     = (const float*)d_in[0];
    const float* W_qkv = (const float*)d_in[1];
    const float* b_qkv = (const float*)d_in[2];
    const float* W_out = (const float*)d_in[3];
    const float* b_out = (const float*)d_in[4];

    float* out  = (float*)d_out;                    // [B,S,D] f32
    float* attn = out + (size_t)BS * S * D;         // [B,H,S,S] f32

    char* ws = (char*)d_ws;
    unsigned short* xb   = (unsigned short*)(ws);                    // [4096][1024]
    unsigned short* wqT  = (unsigned short*)(ws + 8388608);          // [3072][1024]
    unsigned short* woT  = (unsigned short*)(ws + 14680064);         // [1024][1024]
    unsigned short* Qf   = (unsigned short*)(ws + 16777216);         // frag layout
    unsigned short* Kf   = (unsigned short*)(ws + 25165824);         // frag layout
    unsigned short* Vf   = (unsigned short*)(ws + 33554432);         // frag layout
    unsigned short* vtb  = (unsigned short*)(ws + 41943040);         // [4096][1024]
    float*          invl = (float*)(ws + 50331648);                  // [BH*S]

    k_cvt<<<4096, 256, 0, stream>>>(x, xb, (BS * S * D) / 4);
    k_tr<<<dim3(48, 16), 256, 0, stream>>>(W_qkv, wqT, D, 3 * D);
    k_tr<<<dim3(16, 16), 256, 0, stream>>>(W_out, woT, D, D);

    k_qkv<<<dim3(32, 24), 256, 0, stream>>>(wqT, xb, b_qkv, Qf, Kf, Vf);
    k_den<<<1024, 256, 0, stream>>>(Qf, Kf, invl);
    k_attn2<<<1024, 256, 0, stream>>>(Qf, Kf, Vf, invl, attn, vtb);
    k_out<<<dim3(32, 8), 256, 0, stream>>>(woT, vtb, b_out, out);   // x=m(32), y=n(8)
}

// Round 8
// 250.217 us; speedup vs baseline: 5.0819x; 1.0592x over previous
//
#include <hip/hip_runtime.h>
#include <hip/hip_bf16.h>
#include <cstddef>
#include <cstdint>

typedef __attribute__((ext_vector_type(8))) short short8;   // 8 bf16 (4 VGPR)
typedef __attribute__((ext_vector_type(4))) float f32x4;    // MFMA C/D frag
typedef __attribute__((ext_vector_type(4))) unsigned short us4;

constexpr int BS = 2;     // batch
constexpr int S  = 2048;
constexpr int D  = 1024;
constexpr int H  = 16;
constexpr int HD = 64;
constexpr int BH = BS * H;                  // 32
constexpr float QSCALE = 0.18033688011112042f;  // 0.125 * log2(e)

// f32 -> bf16 round-to-nearest-even (scalar)
__device__ __forceinline__ unsigned short f2bf(float x) {
    unsigned u = __builtin_bit_cast(unsigned, x);
    u += 0x7fffu + ((u >> 16) & 1u);
    return (unsigned short)(u >> 16);
}

// packed f32 pair -> 2 bf16 in one u32 (lo = a, hi = b)
__device__ __forceinline__ unsigned pkbf(float a, float b) {
    unsigned r;
    asm("v_cvt_pk_bf16_f32 %0, %1, %2" : "=v"(r) : "v"(a), "v"(b));
    return r;
}

// native 2^x
__device__ __forceinline__ float fexp2(float x) {
    float r; asm("v_exp_f32 %0, %1" : "=v"(r) : "v"(x)); return r;
}

__device__ __forceinline__ f32x4 MFMA(short8 a, short8 b, f32x4 c) {
    return __builtin_amdgcn_mfma_f32_16x16x32_bf16(a, b, c, 0, 0, 0);
}

// ---------------------------------------------------------------------------
// Async staging (m97-style): 16384-B tile = 128 rows x 128 B, LINEAR LDS.
// ---------------------------------------------------------------------------
__device__ __forceinline__ void stage_async(char* lds, const char* g,
                                            int gstride, int tid) {
    const int w = tid >> 6, l = tid & 63;
#pragma unroll
    for (int i = 0; i < 4; ++i) {
        const int fb = i * 4096 + w * 1024;          // wave-uniform
        const int f  = fb + l * 16;
        const int row = f >> 7, colb = f & 127;
        __builtin_amdgcn_global_load_lds(
            (const __attribute__((address_space(1))) uint32_t*)(g + (size_t)row * gstride + colb),
            (__attribute__((address_space(3))) uint32_t*)(lds + fb),
            16, 0, 0);
    }
}

// linear fragment load
__device__ __forceinline__ short8 fldl(const char* lds, int row, int kb) {
    return *(const short8*)(lds + row * 128 + kb);
}

// swizzled fragment load (attention P tile only)
__device__ __forceinline__ short8 fld(const char* lds, int row, int kb) {
    return *(const short8*)(lds + row * 128 + (kb ^ ((row & 7) << 4)));
}

// ---------------------------------------------------------------------------
// k_prep: fused input conversion + weight transposes (3 old launches -> 1).
//   bid <  4096        : x f32 -> xb bf16 (copy)
//   4096 <= bid < 4864 : W_qkv [1024][3072] -> wqT bf16 [3072][1024]
//   4864 <= bid < 5120 : W_out [1024][1024] -> woT bf16 [1024][1024]
// Whole block takes one branch; __syncthreads only in transpose path.
// ---------------------------------------------------------------------------
__global__ __launch_bounds__(256) void k_prep(const float* __restrict__ x,
                                              unsigned short* __restrict__ xb,
                                              const float* __restrict__ Wq,
                                              unsigned short* __restrict__ wqT,
                                              const float* __restrict__ Wo,
                                              unsigned short* __restrict__ woT) {
    __shared__ float t[64][65];
    const int bid = blockIdx.x;
    if (bid < 4096) {
        const int i = bid * 256 + threadIdx.x;
        f32x4 v = ((const f32x4*)x)[i];
        us4 o = {f2bf(v[0]), f2bf(v[1]), f2bf(v[2]), f2bf(v[3])};
        ((us4*)xb)[i] = o;
        return;
    }
    const float* src; unsigned short* dst; int N, bx, by;
    if (bid < 4864) { const int b2 = bid - 4096; src = Wq; dst = wqT; N = 3072; bx = b2 % 48; by = b2 / 48; }
    else            { const int b3 = bid - 4864; src = Wo; dst = woT; N = 1024; bx = b3 % 16; by = b3 / 16; }
    const int K = 1024;
    const int k0 = by * 64, n0 = bx * 64;
    const int rr = threadIdx.x >> 4, c4 = (threadIdx.x & 15) * 4;
#pragma unroll
    for (int u = 0; u < 4; ++u) {
        int r = rr + u * 16;
        f32x4 v = *(const f32x4*)(src + (size_t)(k0 + r) * N + n0 + c4);
        t[r][c4 + 0] = v[0]; t[r][c4 + 1] = v[1];
        t[r][c4 + 2] = v[2]; t[r][c4 + 3] = v[3];
    }
    __syncthreads();
#pragma unroll
    for (int u = 0; u < 4; ++u) {
        int r = rr + u * 16;
        us4 o = {f2bf(t[c4 + 0][r]), f2bf(t[c4 + 1][r]),
                 f2bf(t[c4 + 2][r]), f2bf(t[c4 + 3][r])};
        *(us4*)(dst + (size_t)(n0 + r) * K + k0 + c4) = o;
    }
}

// ---------------------------------------------------------------------------
// GEMM core (m97 structure): 128(n) x 128(m) tile, BK=64, 4 waves (2n x 2m).
// ---------------------------------------------------------------------------
__device__ __forceinline__ void gemm_core(const char* Ag, const char* Bg,
                                          char* lA, char* lB, int tid,
                                          f32x4 (&acc)[4][4]) {
    const int l = tid & 63, g = l >> 4, li = l & 15;
    const int w = tid >> 6, wn = w >> 1, wm = w & 1;
    for (int k0 = 0; k0 < 1024; k0 += 64) {
        __syncthreads();
        stage_async(lA, Ag + k0 * 2, 2048, tid);
        stage_async(lB, Bg + k0 * 2, 2048, tid);
        __syncthreads();   // compiler drains vmcnt(0) before barrier
#pragma unroll
        for (int kf = 0; kf < 2; ++kf) {
            short8 a[4], b[4];
#pragma unroll
            for (int i = 0; i < 4; ++i) a[i] = fldl(lA, wn * 64 + i * 16 + li, kf * 64 + g * 16);
#pragma unroll
            for (int i = 0; i < 4; ++i) b[i] = fldl(lB, wm * 64 + i * 16 + li, kf * 64 + g * 16);
#pragma unroll
            for (int i = 0; i < 4; ++i)
#pragma unroll
                for (int j = 0; j < 4; ++j) acc[i][j] = MFMA(a[i], b[j], acc[i][j]);
        }
    }
}

// ---------------------------------------------------------------------------
// QKV projection: A = WqT [3072][1024], B = xb [4096][1024].
// Epilogue scatters into MFMA-fragment layouts:
//   Qf: [bh][qt=s/16][kf=d/32][lane=g*16+(s%16)][j=d%8]   (QSCALE folded)
//   Kf: [bh][t=s/64][kf=d/32][i=(s/16)%4][lane=g*16+(s%16)][j=d%8]
//   Vf: [bh][t][kvf=(s/32)%2][df=d/16][lane=gv*16+(d%16)][j=s%8]
// ---------------------------------------------------------------------------
__global__ __launch_bounds__(256) void k_qkv(const unsigned short* __restrict__ WqT,
                                             const unsigned short* __restrict__ xb,
                                             const float* __restrict__ bias,
                                             unsigned short* __restrict__ Qf,
                                             unsigned short* __restrict__ Kf,
                                             unsigned short* __restrict__ Vf) {
    __shared__ alignas(16) char lA[16384];
    __shared__ alignas(16) char lB[16384];
    const int tid = threadIdx.x;
    f32x4 acc[4][4] = {};
    const char* Ag = (const char*)(WqT + (size_t)blockIdx.y * 128 * 1024);
    const char* Bg = (const char*)(xb  + (size_t)blockIdx.x * 128 * 1024);
    gemm_core(Ag, Bg, lA, lB, tid, acc);

    const int l = tid & 63, g = l >> 4, li = l & 15;
    const int w = tid >> 6, wn = w >> 1, wm = w & 1;
    const int nBase = blockIdx.y * 128 + wn * 64;
    const int mBase = blockIdx.x * 128 + wm * 64;
#pragma unroll
    for (int i = 0; i < 4; ++i)
#pragma unroll
        for (int j = 0; j < 4; ++j) {
            const int n0 = nBase + i * 16 + g * 4;
            const int m  = mBase + j * 16 + li;
            const int bb = m >> 11, s = m & (S - 1);
            const int h = n0 / 192, r2 = n0 % 192, tt = r2 >> 6, d0 = r2 & 63;
            const int bh_ = bb * H + h;
            f32x4 v = acc[i][j];
            const f32x4 b4 = *(const f32x4*)(bias + n0);
            v += b4;
            if (tt == 0) {
                v[0] *= QSCALE; v[1] *= QSCALE; v[2] *= QSCALE; v[3] *= QSCALE;
                us4 o = {f2bf(v[0]), f2bf(v[1]), f2bf(v[2]), f2bf(v[3])};
                size_t e = (((size_t)bh_ * 128 + (s >> 4)) * 2 + (d0 >> 5)) * 512
                         + (((d0 & 31) >> 3) * 16 + (s & 15)) * 8 + (d0 & 7);
                *(us4*)(Qf + e) = o;
            } else if (tt == 1) {
                us4 o = {f2bf(v[0]), f2bf(v[1]), f2bf(v[2]), f2bf(v[3])};
                size_t e = ((((size_t)bh_ * 32 + (s >> 6)) * 2 + (d0 >> 5)) * 4
                            + ((s >> 4) & 3)) * 512
                         + (((d0 & 31) >> 3) * 16 + (s & 15)) * 8 + (d0 & 7);
                *(us4*)(Kf + e) = o;
            } else {
                size_t vbase = ((((size_t)bh_ * 32 + (s >> 6)) * 2 + ((s >> 5) & 1)) * 4
                                + (d0 >> 4)) * 512
                             + ((s >> 3) & 3) * 128 + (s & 7);
#pragma unroll
                for (int r = 0; r < 4; ++r)
                    Vf[vbase + ((d0 & 15) + r) * 8] = f2bf(v[r]);
            }
        }
}

// ---------------------------------------------------------------------------
// Output projection: A = WoT [1024][1024], B = vtb [4096][1024], f32 out + bias
// grid MUST be dim3(32, 8): x -> m tiles, y -> n tiles.
// ---------------------------------------------------------------------------
__global__ __launch_bounds__(256) void k_out(const unsigned short* __restrict__ WoT,
                                             const unsigned short* __restrict__ vtb,
                                             const float* __restrict__ bias,
                                             float* __restrict__ outp) {
    __shared__ alignas(16) char lA[16384];
    __shared__ alignas(16) char lB[16384];
    const int tid = threadIdx.x;
    f32x4 acc[4][4] = {};
    const char* Ag = (const char*)(WoT + (size_t)blockIdx.y * 128 * 1024);
    const char* Bg = (const char*)(vtb + (size_t)blockIdx.x * 128 * 1024);
    gemm_core(Ag, Bg, lA, lB, tid, acc);

    const int l = tid & 63, g = l >> 4, li = l & 15;
    const int w = tid >> 6, wn = w >> 1, wm = w & 1;
    const int nBase = blockIdx.y * 128 + wn * 64;
    const int mBase = blockIdx.x * 128 + wm * 64;
#pragma unroll
    for (int i = 0; i < 4; ++i)
#pragma unroll
        for (int j = 0; j < 4; ++j) {
            const int n0 = nBase + i * 16 + g * 4;
            const int m  = mBase + j * 16 + li;
            f32x4 v = acc[i][j];
            const f32x4 b4 = *(const f32x4*)(bias + n0);
            v += b4;
            *(f32x4*)(outp + (size_t)m * D + n0) = v;
        }
}

// ---------------------------------------------------------------------------
// Attention helpers
// ---------------------------------------------------------------------------
__device__ __forceinline__ void ldfr(short8 (&b)[8], const short8* base, int l) {
#pragma unroll
    for (int f = 0; f < 8; ++f) b[f] = base[f * 64 + l];
}

// ---------------------------------------------------------------------------
// k_attn: FUSED denominator pass + prob/PV pass (identical 16-q-row/wave
// decomposition -> invl stays in registers; no invl buffer, no second kernel).
// Grid 1024 (XCD-swizzled), single kv[8] register block time-shared K/V.
// ---------------------------------------------------------------------------
__global__ __launch_bounds__(256, 4) void k_attn(const unsigned short* __restrict__ Qf,
                                                 const unsigned short* __restrict__ Kf,
                                                 const unsigned short* __restrict__ Vf,
                                                 float* __restrict__ attn,
                                                 unsigned short* __restrict__ vtb) {
    __shared__ alignas(16) char lP[8192];
    const int tid = threadIdx.x;
    const int w = tid >> 6, l = tid & 63, g = l >> 4, li = l & 15;
    const int wid = (blockIdx.x & 7) * 128 + (blockIdx.x >> 3);   // XCD swizzle
    const int bh = wid >> 5, bx = wid & 31;
    const int b = bh >> 4, h = bh & 15;
    const int q0 = bx * 64 + w * 16;
    char* pb = lP + w * 2048;   // per-wave [16 q][64 kv] bf16, swizzled

    const short8* Q8 = (const short8*)Qf;
    const short8* Kt8 = (const short8*)Kf + (size_t)bh * 16384;
    const short8* Vt8 = (const short8*)Vf + (size_t)bh * 16384;
    float* attnb = attn + (size_t)bh * S * S;

    short8 qfr[2];
#pragma unroll
    for (int kf = 0; kf < 2; ++kf)
        qfr[kf] = Q8[(((size_t)bh * 128 + (q0 >> 4)) * 2 + kf) * 64 + l];

    short8 kv[8];

    // ---- pass 1: denominator (register-resident) ----
    float run = 0.f;
    ldfr(kv, Kt8, l);
    for (int t = 0; t < 32; ++t) {
        f32x4 sc[4] = {};
        __builtin_amdgcn_s_setprio(1);
#pragma unroll
        for (int kf = 0; kf < 2; ++kf)
#pragma unroll
            for (int i = 0; i < 4; ++i)
                sc[i] = MFMA(kv[kf * 4 + i], qfr[kf], sc[i]);
        __builtin_amdgcn_s_setprio(0);
        if (t < 31) ldfr(kv, Kt8 + (t + 1) * 512, l);   // next K under exp phase
        float part = 0.f;
#pragma unroll
        for (int i = 0; i < 4; ++i)
#pragma unroll
            for (int r = 0; r < 4; ++r) part += fexp2(sc[i][r]);
        run += part;
    }
    run += __shfl_xor(run, 16);
    run += __shfl_xor(run, 32);
    const float invl = 1.0f / run;

    // ---- pass 2: probs + PV ----
    f32x4 oacc[4] = {};   // [dfrag], D[d = df*16+g*4+r][q = li]
    ldfr(kv, Kt8, l);
    for (int t = 0; t < 32; ++t) {
        f32x4 sc[4] = {};
        __builtin_amdgcn_s_setprio(1);
#pragma unroll
        for (int kf = 0; kf < 2; ++kf)
#pragma unroll
            for (int i = 0; i < 4; ++i)
                sc[i] = MFMA(kv[kf * 4 + i], qfr[kf], sc[i]);
        __builtin_amdgcn_s_setprio(0);
        ldfr(kv, Vt8 + t * 512, l);   // V(t) in flight under exp/store phase

#pragma unroll
        for (int i = 0; i < 4; ++i) {
            f32x4 p;
#pragma unroll
            for (int r = 0; r < 4; ++r) p[r] = fexp2(sc[i][r]) * invl;
            __builtin_nontemporal_store(
                p, (f32x4*)(attnb + (size_t)(q0 + li) * S + t * 64 + i * 16 + g * 4));
            uint2 o = {pkbf(p[0], p[1]), pkbf(p[2], p[3])};
            *(uint2*)(pb + li * 128 + ((i * 32 + g * 8) ^ ((li & 7) << 4))) = o;
        }
        short8 pa[2];
#pragma unroll
        for (int kvf = 0; kvf < 2; ++kvf)
            pa[kvf] = fld(pb, li, kvf * 64 + g * 16);
        __builtin_amdgcn_s_setprio(1);
#pragma unroll
        for (int kvf = 0; kvf < 2; ++kvf)
#pragma unroll
            for (int df = 0; df < 4; ++df)
                oacc[df] = MFMA(kv[kvf * 4 + df], pa[kvf], oacc[df]);
        __builtin_amdgcn_s_setprio(0);
        if (t < 31) ldfr(kv, Kt8 + (t + 1) * 512, l);   // K(t+1) in flight
    }

    // vtb [B*S][H*HD] bf16
#pragma unroll
    for (int df = 0; df < 4; ++df) {
        const int qrow = q0 + li;
        const size_t m = (size_t)b * S + qrow;
        const int d0 = df * 16 + g * 4;
        uint2 o = {pkbf(oacc[df][0], oacc[df][1]),
                   pkbf(oacc[df][2], oacc[df][3])};
        *(uint2*)(vtb + m * D + h * HD + d0) = o;
    }
}

// ---------------------------------------------------------------------------
extern "C" void kernel_launch(void* const* d_in, const int* in_sizes, int n_in,
                              void* d_out, int out_size, void* d_ws, size_t ws_size,
                              hipStream_t stream) {
    const float* x     = (const float*)d_in[0];
    const float* W_qkv = (const float*)d_in[1];
    const float* b_qkv = (const float*)d_in[2];
    const float* W_out = (const float*)d_in[3];
    const float* b_out = (const float*)d_in[4];

    float* out  = (float*)d_out;                    // [B,S,D] f32
    float* attn = out + (size_t)BS * S * D;         // [B,H,S,S] f32

    char* ws = (char*)d_ws;
    unsigned short* xb   = (unsigned short*)(ws);                    // [4096][1024]
    unsigned short* wqT  = (unsigned short*)(ws + 8388608);          // [3072][1024]
    unsigned short* woT  = (unsigned short*)(ws + 14680064);         // [1024][1024]
    unsigned short* Qf   = (unsigned short*)(ws + 16777216);         // frag layout
    unsigned short* Kf   = (unsigned short*)(ws + 25165824);         // frag layout
    unsigned short* Vf   = (unsigned short*)(ws + 33554432);         // frag layout
    unsigned short* vtb  = (unsigned short*)(ws + 41943040);         // [4096][1024]

    k_prep<<<5120, 256, 0, stream>>>(x, xb, W_qkv, wqT, W_out, woT);
    k_qkv<<<dim3(32, 24), 256, 0, stream>>>(wqT, xb, b_qkv, Qf, Kf, Vf);
    k_attn<<<1024, 256, 0, stream>>>(Qf, Kf, Vf, attn, vtb);
    k_out<<<dim3(32, 8), 256, 0, stream>>>(woT, vtb, b_out, out);   // x=m(32), y=n(8)
}

// Round 9
// 245.110 us; speedup vs baseline: 5.1878x; 1.0208x over previous
//
#include <hip/hip_runtime.h>
#include <hip/hip_bf16.h>
#include <cstddef>
#include <cstdint>

typedef __attribute__((ext_vector_type(8))) short short8;   // 8 bf16 (4 VGPR)
typedef __attribute__((ext_vector_type(4))) float f32x4;    // MFMA C/D frag
typedef __attribute__((ext_vector_type(4))) unsigned short us4;
typedef __attribute__((ext_vector_type(8))) unsigned short us8;

constexpr int BS = 2;     // batch
constexpr int S  = 2048;
constexpr int D  = 1024;
constexpr int H  = 16;
constexpr int HD = 64;
constexpr int BH = BS * H;                  // 32
constexpr float QSCALE = 0.18033688011112042f;  // 0.125 * log2(e)

// f32 -> bf16 round-to-nearest-even (scalar)
__device__ __forceinline__ unsigned short f2bf(float x) {
    unsigned u = __builtin_bit_cast(unsigned, x);
    u += 0x7fffu + ((u >> 16) & 1u);
    return (unsigned short)(u >> 16);
}

// packed f32 pair -> 2 bf16 in one u32 (lo = a, hi = b)
__device__ __forceinline__ unsigned pkbf(float a, float b) {
    unsigned r;
    asm("v_cvt_pk_bf16_f32 %0, %1, %2" : "=v"(r) : "v"(a), "v"(b));
    return r;
}

// native 2^x
__device__ __forceinline__ float fexp2(float x) {
    float r; asm("v_exp_f32 %0, %1" : "=v"(r) : "v"(x)); return r;
}

__device__ __forceinline__ f32x4 MFMA(short8 a, short8 b, f32x4 c) {
    return __builtin_amdgcn_mfma_f32_16x16x32_bf16(a, b, c, 0, 0, 0);
}

// ---------------------------------------------------------------------------
// Async staging (m97-style): tiles of 128-B rows, LINEAR LDS.
// kb1024: number of 1KB-per-wave chunks (4 => 16KB tile, 2 => 8KB tile).
// ---------------------------------------------------------------------------
template<int CH>
__device__ __forceinline__ void stage_async(char* lds, const char* g,
                                            int gstride, int tid) {
    const int w = tid >> 6, l = tid & 63;
#pragma unroll
    for (int i = 0; i < CH; ++i) {
        const int fb = i * 4096 + w * 1024;          // wave-uniform
        const int f  = fb + l * 16;
        const int row = f >> 7, colb = f & 127;
        __builtin_amdgcn_global_load_lds(
            (const __attribute__((address_space(1))) uint32_t*)(g + (size_t)row * gstride + colb),
            (__attribute__((address_space(3))) uint32_t*)(lds + fb),
            16, 0, 0);
    }
}

// linear fragment load
__device__ __forceinline__ short8 fldl(const char* lds, int row, int kb) {
    return *(const short8*)(lds + row * 128 + kb);
}

// swizzled fragment load (attention P tile only)
__device__ __forceinline__ short8 fld(const char* lds, int row, int kb) {
    return *(const short8*)(lds + row * 128 + (kb ^ ((row & 7) << 4)));
}

// ---------------------------------------------------------------------------
// k_prep: fused input conversion + weight transposes.
//   bid <  4096        : x f32 -> xb bf16 (copy)
//   4096 <= bid < 4864 : W_qkv [1024][3072] -> wqT bf16 [3072][1024]
//   4864 <= bid < 5120 : W_out [1024][1024] -> woT bf16 [1024][1024]
// ---------------------------------------------------------------------------
__global__ __launch_bounds__(256) void k_prep(const float* __restrict__ x,
                                              unsigned short* __restrict__ xb,
                                              const float* __restrict__ Wq,
                                              unsigned short* __restrict__ wqT,
                                              const float* __restrict__ Wo,
                                              unsigned short* __restrict__ woT) {
    __shared__ float t[64][65];
    const int bid = blockIdx.x;
    if (bid < 4096) {
        const int i = bid * 256 + threadIdx.x;
        f32x4 v = ((const f32x4*)x)[i];
        us4 o = {f2bf(v[0]), f2bf(v[1]), f2bf(v[2]), f2bf(v[3])};
        ((us4*)xb)[i] = o;
        return;
    }
    const float* src; unsigned short* dst; int N, bx, by;
    if (bid < 4864) { const int b2 = bid - 4096; src = Wq; dst = wqT; N = 3072; bx = b2 % 48; by = b2 / 48; }
    else            { const int b3 = bid - 4864; src = Wo; dst = woT; N = 1024; bx = b3 % 16; by = b3 / 16; }
    const int K = 1024;
    const int k0 = by * 64, n0 = bx * 64;
    const int rr = threadIdx.x >> 4, c4 = (threadIdx.x & 15) * 4;
#pragma unroll
    for (int u = 0; u < 4; ++u) {
        int r = rr + u * 16;
        f32x4 v = *(const f32x4*)(src + (size_t)(k0 + r) * N + n0 + c4);
        t[r][c4 + 0] = v[0]; t[r][c4 + 1] = v[1];
        t[r][c4 + 2] = v[2]; t[r][c4 + 3] = v[3];
    }
    __syncthreads();
#pragma unroll
    for (int u = 0; u < 4; ++u) {
        int r = rr + u * 16;
        us4 o = {f2bf(t[c4 + 0][r]), f2bf(t[c4 + 1][r]),
                 f2bf(t[c4 + 2][r]), f2bf(t[c4 + 3][r])};
        *(us4*)(dst + (size_t)(n0 + r) * K + k0 + c4) = o;
    }
}

// ---------------------------------------------------------------------------
// GEMM core (m97 structure): 128(n) x 128(m) tile, BK=64, 4 waves (2n x 2m).
// acc[i][j][r] = C[m = mBase + j*16 + li][n = nBase + i*16 + g*4 + r]
// ---------------------------------------------------------------------------
__device__ __forceinline__ void gemm_core(const char* Ag, const char* Bg,
                                          char* lA, char* lB, int tid,
                                          f32x4 (&acc)[4][4]) {
    const int l = tid & 63, g = l >> 4, li = l & 15;
    const int w = tid >> 6, wn = w >> 1, wm = w & 1;
    for (int k0 = 0; k0 < 1024; k0 += 64) {
        __syncthreads();
        stage_async<4>(lA, Ag + k0 * 2, 2048, tid);
        stage_async<4>(lB, Bg + k0 * 2, 2048, tid);
        __syncthreads();   // compiler drains vmcnt(0) before barrier
#pragma unroll
        for (int kf = 0; kf < 2; ++kf) {
            short8 a[4], b[4];
#pragma unroll
            for (int i = 0; i < 4; ++i) a[i] = fldl(lA, wn * 64 + i * 16 + li, kf * 64 + g * 16);
#pragma unroll
            for (int i = 0; i < 4; ++i) b[i] = fldl(lB, wm * 64 + i * 16 + li, kf * 64 + g * 16);
#pragma unroll
            for (int i = 0; i < 4; ++i)
#pragma unroll
                for (int j = 0; j < 4; ++j) acc[i][j] = MFMA(a[i], b[j], acc[i][j]);
        }
    }
}

// ---------------------------------------------------------------------------
// QKV projection: A = WqT [3072][1024], B = xb [4096][1024].
// Each wave's 64-wide n-window is 64-aligned => q/k/v type is WAVE-UNIFORM.
// Q/K: direct fragment-layout scatter (us4, as verified rounds 3-8).
// V: per-wave LDS transpose [d][s] then coalesced us8 stores (same Vf
//    element formula as before; only the store pattern changed).
//   Qf: [bh][qt=s/16][kf=d/32][lane=g*16+(s%16)][j=d%8]   (QSCALE folded)
//   Kf: [bh][t=s/64][kf=d/32][i=(s/16)%4][lane=g*16+(s%16)][j=d%8]
//   Vf: [bh][t][kvf=(s/32)%2][df=d/16][lane=gv*16+(d%16)][j=s%8]
// ---------------------------------------------------------------------------
__global__ __launch_bounds__(256) void k_qkv(const unsigned short* __restrict__ WqT,
                                             const unsigned short* __restrict__ xb,
                                             const float* __restrict__ bias,
                                             unsigned short* __restrict__ Qf,
                                             unsigned short* __restrict__ Kf,
                                             unsigned short* __restrict__ Vf) {
    __shared__ alignas(16) char lds[32768];
    char* lA = lds;
    char* lB = lds + 16384;
    const int tid = threadIdx.x;
    f32x4 acc[4][4] = {};
    const char* Ag = (const char*)(WqT + (size_t)blockIdx.y * 128 * 1024);
    const char* Bg = (const char*)(xb  + (size_t)blockIdx.x * 128 * 1024);
    gemm_core(Ag, Bg, lA, lB, tid, acc);

    const int l = tid & 63, g = l >> 4, li = l & 15;
    const int w = tid >> 6, wn = w >> 1, wm = w & 1;
    const int nWbase = blockIdx.y * 128 + wn * 64;   // wave n-window (64-aligned)
    const int mBaseW = blockIdx.x * 128 + wm * 64;   // wave m-window
    const int r2w = nWbase % 192;
    const int ttw = r2w >> 6;                        // wave-uniform type
    const int hW  = nWbase / 192;
    const int bbW = mBaseW >> 11;                    // batch uniform per block
    const int bhW = bbW * H + hW;

    __syncthreads();   // gemm's last LDS reads must finish before reuse

    if (ttw == 2) {
        // ---- V path: LDS transpose to [d][s] (bf16, XOR-swizzled) ----
        char* buf = lds + w * 8192;   // private 8KB per wave
#pragma unroll
        for (int i = 0; i < 4; ++i)
#pragma unroll
            for (int j = 0; j < 4; ++j) {
                const int n0 = nWbase + i * 16 + g * 4;
                const f32x4 b4 = *(const f32x4*)(bias + n0);
                f32x4 v = acc[i][j];
                v += b4;
                const int sl = j * 16 + li;
#pragma unroll
                for (int r = 0; r < 4; ++r) {
                    const int d = i * 16 + g * 4 + r;   // r2w&63 == 0 for V windows
                    *(unsigned short*)(buf + ((d * 128 + sl * 2) ^ ((d & 7) << 4)))
                        = f2bf(v[r]);
                }
            }
        // lgkm wait handled by compiler; buffer is wave-private (no barrier)
#pragma unroll
        for (int it = 0; it < 8; ++it) {
            const int d = l;
            us8 val = *(const us8*)(buf + ((d * 128 + it * 16) ^ ((d & 7) << 4)));
            const int s = (mBaseW & (S - 1)) + it * 8;   // block is batch-uniform
            size_t e = ((((size_t)bhW * 32 + (s >> 6)) * 2 + ((s >> 5) & 1)) * 4
                        + (d >> 4)) * 512
                     + ((s >> 3) & 3) * 128 + (d & 15) * 8;
            *(us8*)(Vf + e) = val;
        }
        return;
    }

    // ---- Q/K path: direct scatter (identical to verified code) ----
#pragma unroll
    for (int i = 0; i < 4; ++i)
#pragma unroll
        for (int j = 0; j < 4; ++j) {
            const int n0 = nWbase + i * 16 + g * 4;
            const int m  = mBaseW + j * 16 + li;
            const int s = m & (S - 1);
            const int d0 = (r2w & 63) + i * 16 + g * 4;
            f32x4 v = acc[i][j];
            const f32x4 b4 = *(const f32x4*)(bias + n0);
            v += b4;
            if (ttw == 0) {
                v[0] *= QSCALE; v[1] *= QSCALE; v[2] *= QSCALE; v[3] *= QSCALE;
                us4 o = {f2bf(v[0]), f2bf(v[1]), f2bf(v[2]), f2bf(v[3])};
                size_t e = (((size_t)bhW * 128 + (s >> 4)) * 2 + (d0 >> 5)) * 512
                         + (((d0 & 31) >> 3) * 16 + (s & 15)) * 8 + (d0 & 7);
                *(us4*)(Qf + e) = o;
            } else {
                us4 o = {f2bf(v[0]), f2bf(v[1]), f2bf(v[2]), f2bf(v[3])};
                size_t e = ((((size_t)bhW * 32 + (s >> 6)) * 2 + (d0 >> 5)) * 4
                            + ((s >> 4) & 3)) * 512
                         + (((d0 & 31) >> 3) * 16 + (s & 15)) * 8 + (d0 & 7);
                *(us4*)(Kf + e) = o;
            }
        }
}

// ---------------------------------------------------------------------------
// Output projection: A = WoT [1024][1024], B = vtb [4096][1024], f32 out+bias.
// Retiled 64(m) x 128(n) per block, grid (64, 8) -> 512 blocks = 2/CU.
// Waves: wn = w>>1 (n-half), wm = w&1 (m-half); wave tile 64n x 32m.
// acc[i][j][r] = C[m = mBase + wm*32 + j*16 + li][n = nBase + wn*64 + i*16 + g*4 + r]
// grid: blockIdx.x -> m tiles (64), blockIdx.y -> n tiles (8).
// ---------------------------------------------------------------------------
__global__ __launch_bounds__(256) void k_out(const unsigned short* __restrict__ WoT,
                                             const unsigned short* __restrict__ vtb,
                                             const float* __restrict__ bias,
                                             float* __restrict__ outp) {
    __shared__ alignas(16) char lA[16384];   // 128 n-rows x 64 k
    __shared__ alignas(16) char lB[8192];    // 64 m-rows x 64 k
    const int tid = threadIdx.x;
    const int l = tid & 63, g = l >> 4, li = l & 15;
    const int w = tid >> 6, wn = w >> 1, wm = w & 1;
    const char* Ag = (const char*)(WoT + (size_t)blockIdx.y * 128 * 1024);
    const char* Bg = (const char*)(vtb + (size_t)blockIdx.x * 64 * 1024);

    f32x4 acc[4][2] = {};
    for (int k0 = 0; k0 < 1024; k0 += 64) {
        __syncthreads();
        stage_async<4>(lA, Ag + k0 * 2, 2048, tid);
        stage_async<2>(lB, Bg + k0 * 2, 2048, tid);
        __syncthreads();
#pragma unroll
        for (int kf = 0; kf < 2; ++kf) {
            short8 a[4], b[2];
#pragma unroll
            for (int i = 0; i < 4; ++i) a[i] = fldl(lA, wn * 64 + i * 16 + li, kf * 64 + g * 16);
#pragma unroll
            for (int j = 0; j < 2; ++j) b[j] = fldl(lB, wm * 32 + j * 16 + li, kf * 64 + g * 16);
#pragma unroll
            for (int i = 0; i < 4; ++i)
#pragma unroll
                for (int j = 0; j < 2; ++j) acc[i][j] = MFMA(a[i], b[j], acc[i][j]);
        }
    }

#pragma unroll
    for (int i = 0; i < 4; ++i)
#pragma unroll
        for (int j = 0; j < 2; ++j) {
            const int n0 = blockIdx.y * 128 + wn * 64 + i * 16 + g * 4;
            const int m  = blockIdx.x * 64 + wm * 32 + j * 16 + li;
            f32x4 v = acc[i][j];
            const f32x4 b4 = *(const f32x4*)(bias + n0);
            v += b4;
            *(f32x4*)(outp + (size_t)m * D + n0) = v;
        }
}

// ---------------------------------------------------------------------------
// Attention helpers
// ---------------------------------------------------------------------------
__device__ __forceinline__ void ldfr(short8 (&b)[8], const short8* base, int l) {
#pragma unroll
    for (int f = 0; f < 8; ++f) b[f] = base[f * 64 + l];
}

// ---------------------------------------------------------------------------
// k_attn: FUSED denominator pass + prob/PV pass (16 q-rows/wave; invl stays
// in registers). Grid 1024 (XCD-swizzled), kv[8] register block time-shared.
// ---------------------------------------------------------------------------
__global__ __launch_bounds__(256, 4) void k_attn(const unsigned short* __restrict__ Qf,
                                                 const unsigned short* __restrict__ Kf,
                                                 const unsigned short* __restrict__ Vf,
                                                 float* __restrict__ attn,
                                                 unsigned short* __restrict__ vtb) {
    __shared__ alignas(16) char lP[8192];
    const int tid = threadIdx.x;
    const int w = tid >> 6, l = tid & 63, g = l >> 4, li = l & 15;
    const int wid = (blockIdx.x & 7) * 128 + (blockIdx.x >> 3);   // XCD swizzle
    const int bh = wid >> 5, bx = wid & 31;
    const int b = bh >> 4, h = bh & 15;
    const int q0 = bx * 64 + w * 16;
    char* pb = lP + w * 2048;   // per-wave [16 q][64 kv] bf16, swizzled

    const short8* Q8 = (const short8*)Qf;
    const short8* Kt8 = (const short8*)Kf + (size_t)bh * 16384;
    const short8* Vt8 = (const short8*)Vf + (size_t)bh * 16384;
    float* attnb = attn + (size_t)bh * S * S;

    short8 qfr[2];
#pragma unroll
    for (int kf = 0; kf < 2; ++kf)
        qfr[kf] = Q8[(((size_t)bh * 128 + (q0 >> 4)) * 2 + kf) * 64 + l];

    short8 kv[8];

    // ---- pass 1: denominator (register-resident) ----
    float run = 0.f;
    ldfr(kv, Kt8, l);
    for (int t = 0; t < 32; ++t) {
        f32x4 sc[4] = {};
        __builtin_amdgcn_s_setprio(1);
#pragma unroll
        for (int kf = 0; kf < 2; ++kf)
#pragma unroll
            for (int i = 0; i < 4; ++i)
                sc[i] = MFMA(kv[kf * 4 + i], qfr[kf], sc[i]);
        __builtin_amdgcn_s_setprio(0);
        if (t < 31) ldfr(kv, Kt8 + (t + 1) * 512, l);   // next K under exp phase
        float part = 0.f;
#pragma unroll
        for (int i = 0; i < 4; ++i)
#pragma unroll
            for (int r = 0; r < 4; ++r) part += fexp2(sc[i][r]);
        run += part;
    }
    run += __shfl_xor(run, 16);
    run += __shfl_xor(run, 32);
    const float invl = 1.0f / run;

    // ---- pass 2: probs + PV ----
    f32x4 oacc[4] = {};   // [dfrag], D[d = df*16+g*4+r][q = li]
    ldfr(kv, Kt8, l);
    for (int t = 0; t < 32; ++t) {
        f32x4 sc[4] = {};
        __builtin_amdgcn_s_setprio(1);
#pragma unroll
        for (int kf = 0; kf < 2; ++kf)
#pragma unroll
            for (int i = 0; i < 4; ++i)
                sc[i] = MFMA(kv[kf * 4 + i], qfr[kf], sc[i]);
        __builtin_amdgcn_s_setprio(0);
        ldfr(kv, Vt8 + t * 512, l);   // V(t) in flight under exp/store phase

#pragma unroll
        for (int i = 0; i < 4; ++i) {
            f32x4 p;
#pragma unroll
            for (int r = 0; r < 4; ++r) p[r] = fexp2(sc[i][r]) * invl;
            __builtin_nontemporal_store(
                p, (f32x4*)(attnb + (size_t)(q0 + li) * S + t * 64 + i * 16 + g * 4));
            uint2 o = {pkbf(p[0], p[1]), pkbf(p[2], p[3])};
            *(uint2*)(pb + li * 128 + ((i * 32 + g * 8) ^ ((li & 7) << 4))) = o;
        }
        short8 pa[2];
#pragma unroll
        for (int kvf = 0; kvf < 2; ++kvf)
            pa[kvf] = fld(pb, li, kvf * 64 + g * 16);
        __builtin_amdgcn_s_setprio(1);
#pragma unroll
        for (int kvf = 0; kvf < 2; ++kvf)
#pragma unroll
            for (int df = 0; df < 4; ++df)
                oacc[df] = MFMA(kv[kvf * 4 + df], pa[kvf], oacc[df]);
        __builtin_amdgcn_s_setprio(0);
        if (t < 31) ldfr(kv, Kt8 + (t + 1) * 512, l);   // K(t+1) in flight
    }

    // vtb [B*S][H*HD] bf16
#pragma unroll
    for (int df = 0; df < 4; ++df) {
        const int qrow = q0 + li;
        const size_t m = (size_t)b * S + qrow;
        const int d0 = df * 16 + g * 4;
        uint2 o = {pkbf(oacc[df][0], oacc[df][1]),
                   pkbf(oacc[df][2], oacc[df][3])};
        *(uint2*)(vtb + m * D + h * HD + d0) = o;
    }
}

// ---------------------------------------------------------------------------
extern "C" void kernel_launch(void* const* d_in, const int* in_sizes, int n_in,
                              void* d_out, int out_size, void* d_ws, size_t ws_size,
                              hipStream_t stream) {
    const float* x     = (const float*)d_in[0];
    const float* W_qkv = (const float*)d_in[1];
    const float* b_qkv = (const float*)d_in[2];
    const float* W_out = (const float*)d_in[3];
    const float* b_out = (const float*)d_in[4];

    float* out  = (float*)d_out;                    // [B,S,D] f32
    float* attn = out + (size_t)BS * S * D;         // [B,H,S,S] f32

    char* ws = (char*)d_ws;
    unsigned short* xb   = (unsigned short*)(ws);                    // [4096][1024]
    unsigned short* wqT  = (unsigned short*)(ws + 8388608);          // [3072][1024]
    unsigned short* woT  = (unsigned short*)(ws + 14680064);         // [1024][1024]
    unsigned short* Qf   = (unsigned short*)(ws + 16777216);         // frag layout
    unsigned short* Kf   = (unsigned short*)(ws + 25165824);         // frag layout
    unsigned short* Vf   = (unsigned short*)(ws + 33554432);         // frag layout
    unsigned short* vtb  = (unsigned short*)(ws + 41943040);         // [4096][1024]

    k_prep<<<5120, 256, 0, stream>>>(x, xb, W_qkv, wqT, W_out, woT);
    k_qkv<<<dim3(32, 24), 256, 0, stream>>>(wqT, xb, b_qkv, Qf, Kf, Vf);
    k_attn<<<1024, 256, 0, stream>>>(Qf, Kf, Vf, attn, vtb);
    k_out<<<dim3(64, 8), 256, 0, stream>>>(woT, vtb, b_out, out);   // x=m(64), y=n(8)
}